// Round 1
// baseline (3682.656 us; speedup 1.0000x reference)
//
#include <hip/hip_runtime.h>

#define C 256
#define NPOS 2048
#define BB 8
#define TTIME 4
#define LT 32
#define PRM_STRIDE 132096  // w1fT 65536 | w2fT 65536 | w3T 768 | bias 256

// ---------------- PREP: fold BN params into conv weights ----------------
__global__ __launch_bounds__(256) void prep_kern(
    const float* __restrict__ w1g, const float* __restrict__ bn1,
    const float* __restrict__ w3g, const float* __restrict__ w2g,
    const float* __restrict__ bn2, const float* __restrict__ bno,
    float* __restrict__ prm)
{
    int i = blockIdx.x;
    int tid = threadIdx.x;
    __shared__ float s1l[C], hcl[C], SGl[C];
    const float* b1 = bn1 + i * 4 * C;
    const float* b2 = bn2 + i * 4 * C;
    const float* bo = bno + i * 4 * C;
    float g1 = b1[tid], be1 = b1[C + tid], mu1 = b1[2 * C + tid], va1 = b1[3 * C + tid];
    float s1 = g1 / sqrtf(va1 + 1e-5f);
    float h1 = be1 - mu1 * s1;
    float g2 = b2[tid], be2 = b2[C + tid], mu2 = b2[2 * C + tid], va2 = b2[3 * C + tid];
    float s2 = g2 / sqrtf(va2 + 1e-5f);
    float h2 = be2 - mu2 * s2;
    float go = bo[tid], beo = bo[C + tid], muo = bo[2 * C + tid], vao = bo[3 * C + tid];
    float so = go / sqrtf(vao + 1e-5f);
    float ho = beo - muo * so;
    float SG = so * s2;
    float SH = so * h2 + ho;
    const float* w3i = w3g + i * C * 3;
    float w3s = w3i[tid * 3 + 0] + w3i[tid * 3 + 1] + w3i[tid * 3 + 2];
    s1l[tid] = s1; hcl[tid] = w3s * h1; SGl[tid] = SG;
    __syncthreads();
    float* prmi = prm + (size_t)i * PRM_STRIDE;
    const float* w1i = w1g + (size_t)i * C * C;
    const float* w2i = w2g + (size_t)i * C * C;
    // w1fT[c*256+m] = s1[m]*w1[m][c]   (c = tid, m = k): coalesced reads, strided writes
    for (int k = 0; k < C; ++k)
        prmi[tid * C + k] = s1l[k] * w1i[k * C + tid];
    // w2fT[m*256+o] = SG[o]*w2[o][m]   (m = tid, o = k)
    for (int k = 0; k < C; ++k)
        prmi[65536 + tid * C + k] = SGl[k] * w2i[k * C + tid];
    // w3T[j*256+m]
    for (int j = 0; j < 3; ++j)
        prmi[131072 + j * C + tid] = w3i[tid * 3 + j];
    // bias[o=tid] = SG*sum_m w2[o][m]*hc[m] + SH
    float dot = 0.f;
    for (int k = 0; k < C; ++k)
        dot = fmaf(w2i[tid * C + k], hcl[k], dot);
    prmi[131840 + tid] = SG * dot + SH;
}

// ---------------- fused conv_bn (optionally + LIF + bit-pack) ----------------
template<int PACK>
__global__ __launch_bounds__(256) void conv_kern(
    const float* __restrict__ x, float* __restrict__ y,
    unsigned int* __restrict__ mask, const float* __restrict__ prm,
    float vth)
{
    const float* w1 = prm;
    const float* w2 = prm + 65536;
    const float* w3 = prm + 131072;
    const float* bs = prm + 131840;
    __shared__ __align__(16) float xs[C][36];
    __shared__ __align__(16) float us[C][37];
    int tid = threadIdx.x;
    int tile = blockIdx.x & 63;
    int sb = blockIdx.x >> 6;         // PACK: b ; plain: slice = t*B+b
    int l0 = tile * LT;
    int to = tid >> 3, tl = tid & 7;
    int row0 = to << 3;
    float v[8][4];
    if (PACK) {
#pragma unroll
        for (int r = 0; r < 8; ++r)
#pragma unroll
            for (int j = 0; j < 4; ++j) v[r][j] = 0.f;
    }
    const int nt = PACK ? TTIME : 1;
    for (int tt = 0; tt < nt; ++tt) {
        int slice = PACK ? (tt * BB + sb) : sb;
        const float* xg = x + (size_t)slice * (C * NPOS);
        // ---- load x tile, halo cols l0-1 .. l0+32 (34 cols), zero-pad OOB ----
#pragma unroll
        for (int i = 0; i < 32; ++i) {
            int idx = i * 256 + tid;
            int row = idx >> 5, col = idx & 31;
            int gcol = l0 - 1 + col;
            xs[row][col] = ((unsigned)gcol < (unsigned)NPOS) ? xg[(size_t)row * NPOS + gcol] : 0.f;
        }
        {
            int row = tid >> 1, col = 32 + (tid & 1);
            int gcol = l0 - 1 + col;
            bool ok = (unsigned)gcol < (unsigned)NPOS;
            xs[row][col]       = ok ? xg[(size_t)row * NPOS + gcol] : 0.f;
            xs[row + 128][col] = ok ? xg[(size_t)(row + 128) * NPOS + gcol] : 0.f;
        }
        __syncthreads();
        // ---- stage 1: u' = W1f * x for cols 0..31 (reg tile 8x4) ----
        float acc[8][4];
#pragma unroll
        for (int r = 0; r < 8; ++r)
#pragma unroll
            for (int j = 0; j < 4; ++j) acc[r][j] = 0.f;
        for (int c = 0; c < C; ++c) {
            float4 xv = *(const float4*)&xs[c][tl * 4];
            const float4* wr = (const float4*)(w1 + (c << 8) + row0);
            float4 wa = wr[0], wb = wr[1];
            float wv[8] = {wa.x, wa.y, wa.z, wa.w, wb.x, wb.y, wb.z, wb.w};
            float xvv[4] = {xv.x, xv.y, xv.z, xv.w};
#pragma unroll
            for (int r = 0; r < 8; ++r)
#pragma unroll
                for (int j = 0; j < 4; ++j)
                    acc[r][j] = fmaf(wv[r], xvv[j], acc[r][j]);
        }
#pragma unroll
        for (int r = 0; r < 8; ++r)
#pragma unroll
            for (int j = 0; j < 4; ++j)
                us[row0 + r][tl * 4 + j] = acc[r][j];
        // extra halo cols 32,33 (thread = m row; coalesced w reads)
        {
            float a32 = 0.f, a33 = 0.f;
            for (int c = 0; c < C; ++c) {
                float w = w1[(c << 8) + tid];
                a32 = fmaf(w, xs[c][32], a32);
                a33 = fmaf(w, xs[c][33], a33);
            }
            us[tid][32] = a32;
            us[tid][33] = a33;
        }
        __syncthreads();
        // ---- depthwise 3-tap -> ts (stored into xs) ----
#pragma unroll
        for (int i = 0; i < 32; ++i) {
            int idx = i * 256 + tid;
            int mrow = idx >> 5, l = idx & 31;
            xs[mrow][l] = w3[mrow] * us[mrow][l]
                        + w3[C + mrow] * us[mrow][l + 1]
                        + w3[2 * C + mrow] * us[mrow][l + 2];
        }
        __syncthreads();
        // ---- stage 2: y = W2f * ts + bias ----
#pragma unroll
        for (int r = 0; r < 8; ++r)
#pragma unroll
            for (int j = 0; j < 4; ++j) acc[r][j] = 0.f;
        for (int c = 0; c < C; ++c) {
            float4 xv = *(const float4*)&xs[c][tl * 4];
            const float4* wr = (const float4*)(w2 + (c << 8) + row0);
            float4 wa = wr[0], wb = wr[1];
            float wv[8] = {wa.x, wa.y, wa.z, wa.w, wb.x, wb.y, wb.z, wb.w};
            float xvv[4] = {xv.x, xv.y, xv.z, xv.w};
#pragma unroll
            for (int r = 0; r < 8; ++r)
#pragma unroll
                for (int j = 0; j < 4; ++j)
                    acc[r][j] = fmaf(wv[r], xvv[j], acc[r][j]);
        }
        if (!PACK) {
            float* yg = y + (size_t)slice * (C * NPOS);
#pragma unroll
            for (int r = 0; r < 8; ++r) {
                float b = bs[row0 + r];
                float4 o4 = make_float4(acc[r][0] + b, acc[r][1] + b,
                                        acc[r][2] + b, acc[r][3] + b);
                *(float4*)(yg + (size_t)(row0 + r) * NPOS + l0 + tl * 4) = o4;
            }
        } else {
            unsigned char* sbyte = (unsigned char*)&us[0][0];
#pragma unroll
            for (int r = 0; r < 8; ++r) {
                float b = bs[row0 + r];
#pragma unroll
                for (int j = 0; j < 4; ++j) {
                    float yy = acc[r][j] + b;
                    float vn = v[r][j] + (yy - v[r][j]) * 0.5f;   // v += (x-v)/tau, tau=2
                    int sp = (vn - vth) >= 0.0f;
                    sbyte[(row0 + r) * LT + tl * 4 + j] = (unsigned char)sp;
                    v[r][j] = sp ? 0.f : vn;                      // hard reset
                }
            }
            __syncthreads();
            {
                unsigned int mw = 0;
#pragma unroll
                for (int l = 0; l < 32; ++l)
                    mw |= (sbyte[tid * LT + l] ? 1u : 0u) << l;
                mask[((size_t)slice * C + tid) * 64 + tile] = mw;
            }
        }
    }
}

// ---------------- kv = sum_n k[n,d] v[n,e]  via popcount (exact ints) ----------------
__global__ __launch_bounds__(256) void kv_kern(
    const unsigned int* __restrict__ km_g, const unsigned int* __restrict__ vm_g,
    int* __restrict__ kv_g)
{
    int blk = blockIdx.x;             // (t*B+b)*H + h
    int h = blk & 7;
    int tb = blk >> 3;
    __shared__ unsigned int km[32][65], vm[32][65];
    int tid = threadIdx.x;
#pragma unroll
    for (int i = 0; i < 8; ++i) {
        int idx = i * 256 + tid;
        int d = idx >> 6, w = idx & 63;
        size_t rb = ((size_t)tb * C + h * 32 + d) * 64 + w;
        km[d][w] = km_g[rb];
        vm[d][w] = vm_g[rb];
    }
    __syncthreads();
#pragma unroll
    for (int k = 0; k < 4; ++k) {
        int p = k * 256 + tid;
        int d = p >> 5, e = p & 31;
        int s = 0;
#pragma unroll
        for (int w = 0; w < 64; ++w)
            s += __popc(km[d][w] & vm[e][w]);
        kv_g[(size_t)blk * 1024 + p] = s;
    }
}

// ---------------- a = (q_spk @ kv)*0.125 ; attn LIF (th=0.5) ; write f32 spikes ----------------
__global__ __launch_bounds__(256) void attn_kern(
    const unsigned int* __restrict__ qm_g, const int* __restrict__ kv_g,
    float* __restrict__ abuf)
{
    int blk = blockIdx.x;             // (b*H + h)*8 + chunk
    int chunk = blk & 7;
    int bh = blk >> 3;
    int h = bh & 7, b = bh >> 3;
    int tid = threadIdx.x;
    int m = chunk * 256 + tid;
    __shared__ int kvs[1024];
    __shared__ unsigned int qw[32][8];
    float v[32];
#pragma unroll
    for (int e = 0; e < 32; ++e) v[e] = 0.f;
    for (int t = 0; t < TTIME; ++t) {
        int tb = t * BB + b;
        __syncthreads();
#pragma unroll
        for (int k = 0; k < 4; ++k)
            kvs[k * 256 + tid] = kv_g[((size_t)tb * 8 + h) * 1024 + k * 256 + tid];
        {
            int d = tid >> 3, wi = tid & 7;
            qw[d][wi] = qm_g[((size_t)tb * C + h * 32 + d) * 64 + chunk * 8 + wi];
        }
        __syncthreads();
        int a[32];
#pragma unroll
        for (int e = 0; e < 32; ++e) a[e] = 0;
        int wsel = tid >> 5, bitp = tid & 31;
        for (int d = 0; d < 32; ++d) {
            if ((qw[d][wsel] >> bitp) & 1u) {
                const int* kr = &kvs[d * 32];
#pragma unroll
                for (int e = 0; e < 32; ++e) a[e] += kr[e];
            }
        }
#pragma unroll
        for (int e = 0; e < 32; ++e) {
            float f = (float)a[e] * 0.125f;          // exact dyadic
            v[e] = v[e] + (f - v[e]) * 0.5f;
            int sp = (v[e] - 0.5f) >= 0.0f;
            abuf[((size_t)tb * C + h * 32 + e) * NPOS + m] = sp ? 1.f : 0.f;
            if (sp) v[e] = 0.f;
        }
    }
}

extern "C" void kernel_launch(void* const* d_in, const int* in_sizes, int n_in,
                              void* d_out, int out_size, void* d_ws, size_t ws_size,
                              hipStream_t stream) {
    const float* q   = (const float*)d_in[0];
    const float* k_  = (const float*)d_in[1];
    const float* w1g = (const float*)d_in[2];
    const float* bn1 = (const float*)d_in[3];
    const float* w3g = (const float*)d_in[4];
    const float* w2g = (const float*)d_in[5];
    const float* bn2 = (const float*)d_in[6];
    const float* bno = (const float*)d_in[7];

    float* prm  = (float*)d_ws;                         // 6*132096 floats
    float* buf1 = prm + 6 * PRM_STRIDE;                 // 16777216 floats
    float* abuf = buf1 + 16777216;                      // 16777216 floats
    unsigned int* qmask = (unsigned int*)(abuf + 16777216);  // 524288 u32 each
    unsigned int* kmask = qmask + 524288;
    unsigned int* vmask = kmask + 524288;
    int* kvb = (int*)(vmask + 524288);                  // 262144 int

    prep_kern<<<6, 256, 0, stream>>>(w1g, bn1, w3g, w2g, bn2, bno, prm);

    // q branch: conv_bn(q,0) + LIF -> qmask
    conv_kern<1><<<512, 256, 0, stream>>>(q, nullptr, qmask, prm + 0 * PRM_STRIDE, 1.0f);
    // k branch: conv_bn(.,1) -> buf1 ; conv_bn(.,2)+LIF -> kmask
    conv_kern<0><<<2048, 256, 0, stream>>>(k_, buf1, nullptr, prm + 1 * PRM_STRIDE, 0.f);
    conv_kern<1><<<512, 256, 0, stream>>>(buf1, nullptr, kmask, prm + 2 * PRM_STRIDE, 1.0f);
    // v branch: conv_bn(.,3) -> buf1 ; conv_bn(.,4)+LIF -> vmask
    conv_kern<0><<<2048, 256, 0, stream>>>(k_, buf1, nullptr, prm + 3 * PRM_STRIDE, 0.f);
    conv_kern<1><<<512, 256, 0, stream>>>(buf1, nullptr, vmask, prm + 4 * PRM_STRIDE, 1.0f);

    kv_kern<<<256, 256, 0, stream>>>(kmask, vmask, kvb);
    attn_kern<<<512, 256, 0, stream>>>(qmask, kvb, abuf);

    // final conv_bn(attn_spikes, 5) -> out
    conv_kern<0><<<2048, 256, 0, stream>>>(abuf, (float*)d_out, nullptr, prm + 5 * PRM_STRIDE, 0.f);
}

// Round 2
// 1952.703 us; speedup vs baseline: 1.8859x; 1.8859x over previous
//
#include <hip/hip_runtime.h>

#define C 256
#define NPOS 2048
#define BB 8
#define TTIME 4
#define PRM_STRIDE 132096  // w1fT 65536 | w2fT 65536 | w3T 768 | bias 256

// ---------------- PREP: fold BN params into conv weights ----------------
__global__ __launch_bounds__(256) void prep_kern(
    const float* __restrict__ w1g, const float* __restrict__ bn1,
    const float* __restrict__ w3g, const float* __restrict__ w2g,
    const float* __restrict__ bn2, const float* __restrict__ bno,
    float* __restrict__ prm)
{
    int i = blockIdx.x;
    int tid = threadIdx.x;
    __shared__ float s1l[C], hcl[C], SGl[C];
    const float* b1 = bn1 + i * 4 * C;
    const float* b2 = bn2 + i * 4 * C;
    const float* bo = bno + i * 4 * C;
    float g1 = b1[tid], be1 = b1[C + tid], mu1 = b1[2 * C + tid], va1 = b1[3 * C + tid];
    float s1 = g1 / sqrtf(va1 + 1e-5f);
    float h1 = be1 - mu1 * s1;
    float g2 = b2[tid], be2 = b2[C + tid], mu2 = b2[2 * C + tid], va2 = b2[3 * C + tid];
    float s2 = g2 / sqrtf(va2 + 1e-5f);
    float h2 = be2 - mu2 * s2;
    float go = bo[tid], beo = bo[C + tid], muo = bo[2 * C + tid], vao = bo[3 * C + tid];
    float so = go / sqrtf(vao + 1e-5f);
    float ho = beo - muo * so;
    float SG = so * s2;
    float SH = so * h2 + ho;
    const float* w3i = w3g + i * C * 3;
    float w3s = w3i[tid * 3 + 0] + w3i[tid * 3 + 1] + w3i[tid * 3 + 2];
    s1l[tid] = s1; hcl[tid] = w3s * h1; SGl[tid] = SG;
    __syncthreads();
    float* prmi = prm + (size_t)i * PRM_STRIDE;
    const float* w1i = w1g + (size_t)i * C * C;
    const float* w2i = w2g + (size_t)i * C * C;
    // w1fT[c*256+m] = s1[m]*w1[m][c]
    for (int k = 0; k < C; ++k)
        prmi[tid * C + k] = s1l[k] * w1i[k * C + tid];
    // w2fT[m*256+o] = SG[o]*w2[o][m]
    for (int k = 0; k < C; ++k)
        prmi[65536 + tid * C + k] = SGl[k] * w2i[k * C + tid];
    // w3T[j*256+m]
    for (int j = 0; j < 3; ++j)
        prmi[131072 + j * C + tid] = w3i[tid * 3 + j];
    // bias[o=tid] = SG*sum_m w2[o][m]*hc[m] + SH
    float dot = 0.f;
    for (int k = 0; k < C; ++k)
        dot = fmaf(w2i[tid * C + k], hcl[k], dot);
    prmi[131840 + tid] = SG * dot + SH;
}

// ---------------- GEMM A: ts = depthwise3(W1f * x) ----------------
// xs cols 0..31 <-> gcol l0..l0+31 ; col 32 <-> l0-1 ; col 33 <-> l0+32
template<int SPIKE_IN>
__global__ __launch_bounds__(256, 4) void gemmA_kern(
    const float* __restrict__ x, const unsigned int* __restrict__ xmask,
    float* __restrict__ ts, const float* __restrict__ prm)
{
    const float* w1 = prm;
    const float* w3 = prm + 131072;
    __shared__ __align__(16) float xs[C][36];
    __shared__ float edg[C][2];
    int tid = threadIdx.x;
    int tile = blockIdx.x & 63;
    int slice = blockIdx.x >> 6;
    int l0 = tile * 32;
    if (SPIKE_IN) {
        const unsigned int* mrow = xmask + ((size_t)slice * C + tid) * 64;
        unsigned int mw = mrow[tile];
#pragma unroll
        for (int c = 0; c < 32; ++c)
            xs[tid][c] = (float)((mw >> c) & 1u);
        xs[tid][32] = (tile > 0)  ? (float)((mrow[tile - 1] >> 31) & 1u) : 0.f;
        xs[tid][33] = (tile < 63) ? (float)(mrow[tile + 1] & 1u) : 0.f;
    } else {
        const float* xg = x + (size_t)slice * (C * NPOS);
#pragma unroll
        for (int i = 0; i < 8; ++i) {
            int idx = i * 256 + tid;
            int r = idx >> 3, c4 = idx & 7;
            *(float4*)&xs[r][c4 * 4] = *(const float4*)(xg + (size_t)r * NPOS + l0 + c4 * 4);
        }
        xs[tid][32] = (l0 > 0)    ? xg[(size_t)tid * NPOS + l0 - 1]  : 0.f;
        xs[tid][33] = (l0 < 2016) ? xg[(size_t)tid * NPOS + l0 + 32] : 0.f;
    }
    __syncthreads();
    int to = tid >> 3, tl = tid & 7, row0 = to << 3;
    float acc[8][4];
#pragma unroll
    for (int r = 0; r < 8; ++r)
#pragma unroll
        for (int j = 0; j < 4; ++j) acc[r][j] = 0.f;
    for (int c = 0; c < C; ++c) {
        float4 xv = *(const float4*)&xs[c][tl * 4];
        const float4* wr = (const float4*)(w1 + (c << 8) + row0);
        float4 wa = wr[0], wb = wr[1];
        float wv[8] = {wa.x, wa.y, wa.z, wa.w, wb.x, wb.y, wb.z, wb.w};
        float xvv[4] = {xv.x, xv.y, xv.z, xv.w};
#pragma unroll
        for (int r = 0; r < 8; ++r)
#pragma unroll
            for (int j = 0; j < 4; ++j)
                acc[r][j] = fmaf(wv[r], xvv[j], acc[r][j]);
    }
    // halo columns: u'[l0-1] and u'[l0+32], one row per thread
    {
        float am1 = 0.f, ar = 0.f;
        for (int c = 0; c < C; ++c) {
            float w = w1[(c << 8) + tid];
            am1 = fmaf(w, xs[c][32], am1);
            ar  = fmaf(w, xs[c][33], ar);
        }
        edg[tid][0] = am1;
        edg[tid][1] = ar;
    }
    __syncthreads();
    // depthwise 3-tap from registers (+shfl for cross-thread cols) -> global ts
    float* tg = ts + (size_t)slice * (C * NPOS);
#pragma unroll
    for (int r = 0; r < 8; ++r) {
        int m = row0 + r;
        float w3a = w3[m], w3b = w3[C + m], w3c = w3[2 * C + m];
        float lft = __shfl_up(acc[r][3], 1);
        if (tl == 0) lft = edg[m][0];
        float rgt = __shfl_down(acc[r][0], 1);
        if (tl == 7) rgt = edg[m][1];
        float t0 = w3a * lft       + w3b * acc[r][0] + w3c * acc[r][1];
        float t1 = w3a * acc[r][0] + w3b * acc[r][1] + w3c * acc[r][2];
        float t2 = w3a * acc[r][1] + w3b * acc[r][2] + w3c * acc[r][3];
        float t3 = w3a * acc[r][2] + w3b * acc[r][3] + w3c * rgt;
        *(float4*)(tg + (size_t)m * NPOS + l0 + tl * 4) = make_float4(t0, t1, t2, t3);
    }
}

// ---------------- GEMM B: y = W2f * ts + bias ----------------
__global__ __launch_bounds__(256, 4) void gemmB_kern(
    const float* __restrict__ ts, float* __restrict__ y,
    const float* __restrict__ prm)
{
    const float* w2 = prm + 65536;
    const float* bs = prm + 131840;
    __shared__ __align__(16) float xs[C][36];
    int tid = threadIdx.x;
    int tile = blockIdx.x & 63;
    int slice = blockIdx.x >> 6;
    int l0 = tile * 32;
    const float* xg = ts + (size_t)slice * (C * NPOS);
#pragma unroll
    for (int i = 0; i < 8; ++i) {
        int idx = i * 256 + tid;
        int r = idx >> 3, c4 = idx & 7;
        *(float4*)&xs[r][c4 * 4] = *(const float4*)(xg + (size_t)r * NPOS + l0 + c4 * 4);
    }
    __syncthreads();
    int to = tid >> 3, tl = tid & 7, row0 = to << 3;
    float acc[8][4];
#pragma unroll
    for (int r = 0; r < 8; ++r)
#pragma unroll
        for (int j = 0; j < 4; ++j) acc[r][j] = 0.f;
    for (int c = 0; c < C; ++c) {
        float4 xv = *(const float4*)&xs[c][tl * 4];
        const float4* wr = (const float4*)(w2 + (c << 8) + row0);
        float4 wa = wr[0], wb = wr[1];
        float wv[8] = {wa.x, wa.y, wa.z, wa.w, wb.x, wb.y, wb.z, wb.w};
        float xvv[4] = {xv.x, xv.y, xv.z, xv.w};
#pragma unroll
        for (int r = 0; r < 8; ++r)
#pragma unroll
            for (int j = 0; j < 4; ++j)
                acc[r][j] = fmaf(wv[r], xvv[j], acc[r][j]);
    }
    float* yg = y + (size_t)slice * (C * NPOS);
#pragma unroll
    for (int r = 0; r < 8; ++r) {
        float b = bs[row0 + r];
        float4 o4 = make_float4(acc[r][0] + b, acc[r][1] + b,
                                acc[r][2] + b, acc[r][3] + b);
        *(float4*)(yg + (size_t)(row0 + r) * NPOS + l0 + tl * 4) = o4;
    }
}

// ---------------- LIF + bitpack over T timesteps ----------------
__global__ __launch_bounds__(256) void lif_kern(
    const float* __restrict__ y, unsigned int* __restrict__ mask, float vth)
{
    int g = blockIdx.x * 256 + threadIdx.x;   // 131072 threads = 8b x 256ch x 64w
    int w = g & 63;
    int ch = (g >> 6) & 255;
    int b = g >> 14;
    float v[32];
#pragma unroll
    for (int j = 0; j < 32; ++j) v[j] = 0.f;
    for (int t = 0; t < TTIME; ++t) {
        int slice = t * BB + b;
        const float* yr = y + ((size_t)slice * C + ch) * NPOS + w * 32;
        unsigned int mw = 0;
#pragma unroll
        for (int q4 = 0; q4 < 8; ++q4) {
            float4 yv = *(const float4*)(yr + q4 * 4);
            float ya[4] = {yv.x, yv.y, yv.z, yv.w};
#pragma unroll
            for (int j = 0; j < 4; ++j) {
                int jj = q4 * 4 + j;
                float vn = v[jj] + (ya[j] - v[jj]) * 0.5f;   // tau=2
                int sp = (vn - vth) >= 0.0f;
                mw |= ((unsigned int)sp) << jj;
                v[jj] = sp ? 0.f : vn;                       // hard reset
            }
        }
        mask[((size_t)slice * C + ch) * 64 + w] = mw;
    }
}

// ---------------- kv = sum_n k[n,d] v[n,e]  via popcount (exact ints) ----------------
__global__ __launch_bounds__(256) void kv_kern(
    const unsigned int* __restrict__ km_g, const unsigned int* __restrict__ vm_g,
    int* __restrict__ kv_g)
{
    int blk = blockIdx.x;             // (t*B+b)*H + h
    int h = blk & 7;
    int tb = blk >> 3;
    __shared__ unsigned int km[32][65], vm[32][65];
    int tid = threadIdx.x;
#pragma unroll
    for (int i = 0; i < 8; ++i) {
        int idx = i * 256 + tid;
        int d = idx >> 6, w = idx & 63;
        size_t rb = ((size_t)tb * C + h * 32 + d) * 64 + w;
        km[d][w] = km_g[rb];
        vm[d][w] = vm_g[rb];
    }
    __syncthreads();
#pragma unroll
    for (int k = 0; k < 4; ++k) {
        int p = k * 256 + tid;
        int d = p >> 5, e = p & 31;
        int s = 0;
#pragma unroll
        for (int w = 0; w < 64; ++w)
            s += __popc(km[d][w] & vm[e][w]);
        kv_g[(size_t)blk * 1024 + p] = s;
    }
}

// ---------------- a = (q_spk @ kv)*0.125 ; attn LIF (th=0.5) ; emit bit-mask ----------------
__global__ __launch_bounds__(256) void attn_kern(
    const unsigned int* __restrict__ qm_g, const int* __restrict__ kv_g,
    unsigned int* __restrict__ amask)
{
    int blk = blockIdx.x;             // (b*H + h)*8 + chunk
    int chunk = blk & 7;
    int bh = blk >> 3;
    int h = bh & 7, b = bh >> 3;
    int tid = threadIdx.x;
    __shared__ int kvs[1024];
    __shared__ unsigned int qw[32][8];
    float v[32];
#pragma unroll
    for (int e = 0; e < 32; ++e) v[e] = 0.f;
    for (int t = 0; t < TTIME; ++t) {
        int tb = t * BB + b;
        __syncthreads();
#pragma unroll
        for (int k = 0; k < 4; ++k)
            kvs[k * 256 + tid] = kv_g[((size_t)tb * 8 + h) * 1024 + k * 256 + tid];
        {
            int d = tid >> 3, wi = tid & 7;
            qw[d][wi] = qm_g[((size_t)tb * C + h * 32 + d) * 64 + chunk * 8 + wi];
        }
        __syncthreads();
        int a[32];
#pragma unroll
        for (int e = 0; e < 32; ++e) a[e] = 0;
        int wsel = tid >> 5, bitp = tid & 31;
        for (int d = 0; d < 32; ++d) {
            if ((qw[d][wsel] >> bitp) & 1u) {
                const int* kr = &kvs[d * 32];
#pragma unroll
                for (int e = 0; e < 32; ++e) a[e] += kr[e];
            }
        }
#pragma unroll
        for (int e = 0; e < 32; ++e) {
            float f = (float)a[e] * 0.125f;          // exact dyadic
            v[e] = v[e] + (f - v[e]) * 0.5f;
            int sp = (v[e] - 0.5f) >= 0.0f;
            unsigned long long bb = __ballot(sp);
            if ((tid & 63) == 0) {
                int ch = h * 32 + e;
                unsigned long long* dst = (unsigned long long*)amask
                    + ((size_t)tb * C + ch) * 32 + chunk * 4 + (tid >> 6);
                *dst = bb;
            }
            if (sp) v[e] = 0.f;
        }
    }
}

extern "C" void kernel_launch(void* const* d_in, const int* in_sizes, int n_in,
                              void* d_out, int out_size, void* d_ws, size_t ws_size,
                              hipStream_t stream) {
    const float* q   = (const float*)d_in[0];
    const float* k_  = (const float*)d_in[1];
    const float* w1g = (const float*)d_in[2];
    const float* bn1 = (const float*)d_in[3];
    const float* w3g = (const float*)d_in[4];
    const float* w2g = (const float*)d_in[5];
    const float* bn2 = (const float*)d_in[6];
    const float* bno = (const float*)d_in[7];

    float* prm  = (float*)d_ws;                          // 792576 floats
    float* tsb  = prm + 6 * PRM_STRIDE;                  // 16777216 floats (64MB)
    float* buf1 = tsb + 16777216;                        // 16777216 floats (64MB)
    unsigned int* qmask = (unsigned int*)(buf1 + 16777216);  // 524288 u32 each
    unsigned int* kmask = qmask + 524288;
    unsigned int* vmask = kmask + 524288;
    int* kvb = (int*)(vmask + 524288);                   // 262144 int
    unsigned int* amask = (unsigned int*)buf1;           // overlay: buf1 dead by attn time

    prep_kern<<<6, 256, 0, stream>>>(w1g, bn1, w3g, w2g, bn2, bno, prm);

    // q branch: conv_bn(q,0) -> LIF -> qmask
    gemmA_kern<0><<<2048, 256, 0, stream>>>(q, nullptr, tsb, prm + 0 * PRM_STRIDE);
    gemmB_kern<<<2048, 256, 0, stream>>>(tsb, buf1, prm + 0 * PRM_STRIDE);
    lif_kern<<<512, 256, 0, stream>>>(buf1, qmask, 1.0f);
    // k branch
    gemmA_kern<0><<<2048, 256, 0, stream>>>(k_, nullptr, tsb, prm + 1 * PRM_STRIDE);
    gemmB_kern<<<2048, 256, 0, stream>>>(tsb, buf1, prm + 1 * PRM_STRIDE);
    gemmA_kern<0><<<2048, 256, 0, stream>>>(buf1, nullptr, tsb, prm + 2 * PRM_STRIDE);
    gemmB_kern<<<2048, 256, 0, stream>>>(tsb, buf1, prm + 2 * PRM_STRIDE);
    lif_kern<<<512, 256, 0, stream>>>(buf1, kmask, 1.0f);
    // v branch
    gemmA_kern<0><<<2048, 256, 0, stream>>>(k_, nullptr, tsb, prm + 3 * PRM_STRIDE);
    gemmB_kern<<<2048, 256, 0, stream>>>(tsb, buf1, prm + 3 * PRM_STRIDE);
    gemmA_kern<0><<<2048, 256, 0, stream>>>(buf1, nullptr, tsb, prm + 4 * PRM_STRIDE);
    gemmB_kern<<<2048, 256, 0, stream>>>(tsb, buf1, prm + 4 * PRM_STRIDE);
    lif_kern<<<512, 256, 0, stream>>>(buf1, vmask, 1.0f);

    kv_kern<<<256, 256, 0, stream>>>(kmask, vmask, kvb);
    attn_kern<<<512, 256, 0, stream>>>(qmask, kvb, amask);

    // final conv_bn(attn_spikes, 5) -> out
    gemmA_kern<1><<<2048, 256, 0, stream>>>(nullptr, amask, tsb, prm + 5 * PRM_STRIDE);
    gemmB_kern<<<2048, 256, 0, stream>>>(tsb, (float*)d_out, prm + 5 * PRM_STRIDE);
}

// Round 3
// 1449.309 us; speedup vs baseline: 2.5410x; 1.3473x over previous
//
#include <hip/hip_runtime.h>

#define C 256
#define NPOS 2048
#define BB 8
#define TTIME 4
#define PRM_STRIDE 132096  // w1fT 65536 | w2fT 65536 | w3T 768 | bias 256
#define FRAG_ELEMS 196608  // 8 ks * 16 rt * 3 s * 64 lane * 8 j (bf16)

typedef float f32x4 __attribute__((ext_vector_type(4)));
typedef short short8 __attribute__((ext_vector_type(8)));

static __device__ __forceinline__ unsigned short f2bf(float f) {
    unsigned int u = __float_as_uint(f);
    return (unsigned short)((u + 0x7FFFu + ((u >> 16) & 1u)) >> 16);
}
static __device__ __forceinline__ float bf2f(unsigned short b) {
    return __uint_as_float(((unsigned int)b) << 16);
}
static __device__ __forceinline__ void split3(float f, unsigned short& h,
                                              unsigned short& m, unsigned short& l) {
    h = f2bf(f);
    float r1 = f - bf2f(h);
    m = f2bf(r1);
    float r2 = r1 - bf2f(m);
    l = f2bf(r2);
}

// ---------------- PREP1: fold BN params into conv weights (f32) ----------------
__global__ __launch_bounds__(256) void prep_kern(
    const float* __restrict__ w1g, const float* __restrict__ bn1,
    const float* __restrict__ w3g, const float* __restrict__ w2g,
    const float* __restrict__ bn2, const float* __restrict__ bno,
    float* __restrict__ prm)
{
    int i = blockIdx.x;
    int tid = threadIdx.x;
    __shared__ float s1l[C], hcl[C], SGl[C];
    const float* b1 = bn1 + i * 4 * C;
    const float* b2 = bn2 + i * 4 * C;
    const float* bo = bno + i * 4 * C;
    float g1 = b1[tid], be1 = b1[C + tid], mu1 = b1[2 * C + tid], va1 = b1[3 * C + tid];
    float s1 = g1 / sqrtf(va1 + 1e-5f);
    float h1 = be1 - mu1 * s1;
    float g2 = b2[tid], be2 = b2[C + tid], mu2 = b2[2 * C + tid], va2 = b2[3 * C + tid];
    float s2 = g2 / sqrtf(va2 + 1e-5f);
    float h2 = be2 - mu2 * s2;
    float go = bo[tid], beo = bo[C + tid], muo = bo[2 * C + tid], vao = bo[3 * C + tid];
    float so = go / sqrtf(vao + 1e-5f);
    float ho = beo - muo * so;
    float SG = so * s2;
    float SH = so * h2 + ho;
    const float* w3i = w3g + i * C * 3;
    float w3s = w3i[tid * 3 + 0] + w3i[tid * 3 + 1] + w3i[tid * 3 + 2];
    s1l[tid] = s1; hcl[tid] = w3s * h1; SGl[tid] = SG;
    __syncthreads();
    float* prmi = prm + (size_t)i * PRM_STRIDE;
    const float* w1i = w1g + (size_t)i * C * C;
    const float* w2i = w2g + (size_t)i * C * C;
    // w1fT[c*256+m] = s1[m]*w1[m][c]
    for (int k = 0; k < C; ++k)
        prmi[tid * C + k] = s1l[k] * w1i[k * C + tid];
    // w2fT[m*256+o] = SG[o]*w2[o][m]
    for (int k = 0; k < C; ++k)
        prmi[65536 + tid * C + k] = SGl[k] * w2i[k * C + tid];
    for (int j = 0; j < 3; ++j)
        prmi[131072 + j * C + tid] = w3i[tid * 3 + j];
    float dot = 0.f;
    for (int k = 0; k < C; ++k)
        dot = fmaf(w2i[tid * C + k], hcl[k], dot);
    prmi[131840 + tid] = SG * dot + SH;
}

// ---------------- PREP2: build bf16x3 MFMA A-fragments ----------------
// frag layout: ((((ks*16 + rt)*3 + s)*64 + lane)*8 + j)
// lane l holds A[m = rt*16 + (l&15)][k = ks*32 + (l>>4)*8 + j]
__global__ __launch_bounds__(256) void prep2_kern(
    const float* __restrict__ prm, unsigned short* __restrict__ frags)
{
    int b = blockIdx.x;           // 12 = 6 convs x 2 matrices
    int i = b >> 1, which = b & 1;
    const float* src = prm + (size_t)i * PRM_STRIDE + which * 65536;  // wT[k*256+m]
    unsigned short* dst = frags + (size_t)b * FRAG_ELEMS;
    for (int e = threadIdx.x; e < 65536; e += 256) {
        int m = e & 255, k = e >> 8;
        float w = src[k * 256 + m];
        unsigned short h, mi, lo;
        split3(w, h, mi, lo);
        int ks = k >> 5, kin = k & 31;
        int rt = m >> 4;
        int lane = (m & 15) | (((kin >> 3) & 3) << 4);
        int j = kin & 7;
        size_t base = ((size_t)(ks * 16 + rt) * 3) * 64 * 8 + lane * 8 + j;
        dst[base] = h;
        dst[base + 512] = mi;     // s=1: +64*8
        dst[base + 1024] = lo;    // s=2
    }
}

// ---------------- MFMA GEMM core macro pieces ----------------
// xsp LDS layout: [col 0..63][k 0..255] bf16, byte addr = col*512 + k*2,
// XOR-swizzled with ((col&7)<<4). Pairs of k packed per u32 write.

// GEMM A: u' = W1f * x   (plain GEMM, no depthwise).  SPIKE: x from bitmask.
template<int SPIKE>
__global__ __launch_bounds__(256) void gemmA_mfma(
    const float* __restrict__ x, const unsigned int* __restrict__ xmask,
    float* __restrict__ uo, const unsigned short* __restrict__ frag)
{
    __shared__ unsigned int xsph[8192], xspm[8192], xspl[8192];
    int tid = threadIdx.x;
    int ctile = blockIdx.x & 31;
    int slice = blockIdx.x >> 5;
    int ct0 = ctile * 64;
    int col = tid & 63, csel = tid >> 6;
    if (!SPIKE) {
        const float* xg = x + (size_t)slice * C * NPOS;
#pragma unroll
        for (int i = 0; i < 32; ++i) {
            int c0 = i * 8 + csel * 2;
            float a = xg[(size_t)c0 * NPOS + ct0 + col];
            float b = xg[(size_t)(c0 + 1) * NPOS + ct0 + col];
            unsigned short ah, am, al, bh, bm, bl;
            split3(a, ah, am, al);
            split3(b, bh, bm, bl);
            int w = (((col << 9) + (c0 << 1)) ^ ((col & 7) << 4)) >> 2;
            xsph[w] = (unsigned int)ah | ((unsigned int)bh << 16);
            xspm[w] = (unsigned int)am | ((unsigned int)bm << 16);
            xspl[w] = (unsigned int)al | ((unsigned int)bl << 16);
        }
    } else {
        const unsigned int* mg = xmask + (size_t)slice * C * 64;
        int wsel = (ct0 >> 5) + (col >> 5);
        int bitp = col & 31;
#pragma unroll
        for (int i = 0; i < 32; ++i) {
            int c0 = i * 8 + csel * 2;
            unsigned int wa = mg[c0 * 64 + wsel];
            unsigned int wb = mg[(c0 + 1) * 64 + wsel];
            unsigned int ba = (wa >> bitp) & 1u, bb = (wb >> bitp) & 1u;
            int w = (((col << 9) + (c0 << 1)) ^ ((col & 7) << 4)) >> 2;
            xsph[w] = (ba ? 0x3F80u : 0u) | ((bb ? 0x3F80u : 0u) << 16);
        }
    }
    __syncthreads();
    int lane = tid & 63, wv = tid >> 6;
    int wr0 = wv * 64;
    f32x4 acc[4][4];
#pragma unroll
    for (int a = 0; a < 4; ++a)
#pragma unroll
        for (int b = 0; b < 4; ++b) acc[a][b] = (f32x4)0.f;
    const short8* Ab = (const short8*)frag;
    int lsub = ((lane >> 4) << 4);   // byte offset of k-subgroup within row
#pragma unroll
    for (int ks = 0; ks < 8; ++ks) {
        short8 A[4][3];
#pragma unroll
        for (int rt = 0; rt < 4; ++rt)
#pragma unroll
            for (int s = 0; s < 3; ++s)
                A[rt][s] = Ab[(size_t)((ks * 16 + wv * 4 + rt) * 3 + s) * 64 + lane];
        if (SPIKE) {
            short8 B[4];
#pragma unroll
            for (int ct = 0; ct < 4; ++ct) {
                int bc = ct * 16 + (lane & 15);
                int ba = ((bc << 9) + ks * 64 + lsub) ^ ((bc & 7) << 4);
                B[ct] = *(const short8*)((const char*)xsph + ba);
            }
#pragma unroll
            for (int p = 0; p < 3; ++p)
#pragma unroll
                for (int rt = 0; rt < 4; ++rt)
#pragma unroll
                    for (int ct = 0; ct < 4; ++ct)
                        acc[rt][ct] = __builtin_amdgcn_mfma_f32_16x16x32_bf16(
                            A[rt][p], B[ct], acc[rt][ct], 0, 0, 0);
        } else {
            short8 B[4][3];
#pragma unroll
            for (int ct = 0; ct < 4; ++ct) {
                int bc = ct * 16 + (lane & 15);
                int ba = ((bc << 9) + ks * 64 + lsub) ^ ((bc & 7) << 4);
                B[ct][0] = *(const short8*)((const char*)xsph + ba);
                B[ct][1] = *(const short8*)((const char*)xspm + ba);
                B[ct][2] = *(const short8*)((const char*)xspl + ba);
            }
            const int PA[6] = {0, 0, 1, 0, 2, 1};
            const int PB[6] = {0, 1, 0, 2, 0, 1};
#pragma unroll
            for (int p = 0; p < 6; ++p)
#pragma unroll
                for (int rt = 0; rt < 4; ++rt)
#pragma unroll
                    for (int ct = 0; ct < 4; ++ct)
                        acc[rt][ct] = __builtin_amdgcn_mfma_f32_16x16x32_bf16(
                            A[rt][PA[p]], B[ct][PB[p]], acc[rt][ct], 0, 0, 0);
        }
    }
    float* ug = uo + (size_t)slice * C * NPOS;
    int rbase = wr0 + ((lane >> 4) << 2);
    int cbase = ct0 + (lane & 15);
#pragma unroll
    for (int rt = 0; rt < 4; ++rt)
#pragma unroll
        for (int ct = 0; ct < 4; ++ct)
#pragma unroll
            for (int r = 0; r < 4; ++r)
                ug[(size_t)(rbase + rt * 16 + r) * NPOS + cbase + ct * 16] = acc[rt][ct][r];
}

// GEMM B: y = W2f * depthwise3(u') + bias
__global__ __launch_bounds__(256) void gemmB_mfma(
    const float* __restrict__ uin, float* __restrict__ y,
    const unsigned short* __restrict__ frag, const float* __restrict__ prmi)
{
    __shared__ unsigned int xsph[8192], xspm[8192], xspl[8192];
    int tid = threadIdx.x;
    int ctile = blockIdx.x & 31;
    int slice = blockIdx.x >> 5;
    int ct0 = ctile * 64;
    int col = tid & 63, csel = tid >> 6;
    const float* ug = uin + (size_t)slice * C * NPOS;
    const float* w3p = prmi + 131072;
    int gc = ct0 + col;
#pragma unroll
    for (int i = 0; i < 32; ++i) {
        int c0 = i * 8 + csel * 2;
        unsigned short th[2], tm[2], tl[2];
#pragma unroll
        for (int rr = 0; rr < 2; ++rr) {
            int c = c0 + rr;
            float w3a = w3p[c], w3b = w3p[256 + c], w3c = w3p[512 + c];
            float uC = ug[(size_t)c * NPOS + gc];
            float uL = __shfl_up(uC, 1);
            if (col == 0) uL = (gc > 0) ? ug[(size_t)c * NPOS + gc - 1] : 0.f;
            float uR = __shfl_down(uC, 1);
            if (col == 63) uR = (gc < NPOS - 1) ? ug[(size_t)c * NPOS + gc + 1] : 0.f;
            float t = w3a * uL + w3b * uC + w3c * uR;
            split3(t, th[rr], tm[rr], tl[rr]);
        }
        int w = (((col << 9) + (c0 << 1)) ^ ((col & 7) << 4)) >> 2;
        xsph[w] = (unsigned int)th[0] | ((unsigned int)th[1] << 16);
        xspm[w] = (unsigned int)tm[0] | ((unsigned int)tm[1] << 16);
        xspl[w] = (unsigned int)tl[0] | ((unsigned int)tl[1] << 16);
    }
    __syncthreads();
    int lane = tid & 63, wv = tid >> 6;
    int wr0 = wv * 64;
    f32x4 acc[4][4];
#pragma unroll
    for (int a = 0; a < 4; ++a)
#pragma unroll
        for (int b = 0; b < 4; ++b) acc[a][b] = (f32x4)0.f;
    const short8* Ab = (const short8*)frag;
    int lsub = ((lane >> 4) << 4);
#pragma unroll
    for (int ks = 0; ks < 8; ++ks) {
        short8 A[4][3];
#pragma unroll
        for (int rt = 0; rt < 4; ++rt)
#pragma unroll
            for (int s = 0; s < 3; ++s)
                A[rt][s] = Ab[(size_t)((ks * 16 + wv * 4 + rt) * 3 + s) * 64 + lane];
        short8 B[4][3];
#pragma unroll
        for (int ct = 0; ct < 4; ++ct) {
            int bc = ct * 16 + (lane & 15);
            int ba = ((bc << 9) + ks * 64 + lsub) ^ ((bc & 7) << 4);
            B[ct][0] = *(const short8*)((const char*)xsph + ba);
            B[ct][1] = *(const short8*)((const char*)xspm + ba);
            B[ct][2] = *(const short8*)((const char*)xspl + ba);
        }
        const int PA[6] = {0, 0, 1, 0, 2, 1};
        const int PB[6] = {0, 1, 0, 2, 0, 1};
#pragma unroll
        for (int p = 0; p < 6; ++p)
#pragma unroll
            for (int rt = 0; rt < 4; ++rt)
#pragma unroll
                for (int ct = 0; ct < 4; ++ct)
                    acc[rt][ct] = __builtin_amdgcn_mfma_f32_16x16x32_bf16(
                        A[rt][PA[p]], B[ct][PB[p]], acc[rt][ct], 0, 0, 0);
    }
    const float* bs = prmi + 131840;
    float* yg = y + (size_t)slice * C * NPOS;
    int rbase = wr0 + ((lane >> 4) << 2);
    int cbase = ct0 + (lane & 15);
#pragma unroll
    for (int rt = 0; rt < 4; ++rt)
#pragma unroll
        for (int ct = 0; ct < 4; ++ct)
#pragma unroll
            for (int r = 0; r < 4; ++r) {
                int row = rbase + rt * 16 + r;
                yg[(size_t)row * NPOS + cbase + ct * 16] = acc[rt][ct][r] + bs[row];
            }
}

// ---------------- LIF + bitpack over T timesteps ----------------
__global__ __launch_bounds__(256) void lif_kern(
    const float* __restrict__ y, unsigned int* __restrict__ mask, float vth)
{
    int g = blockIdx.x * 256 + threadIdx.x;
    int w = g & 63;
    int ch = (g >> 6) & 255;
    int b = g >> 14;
    float v[32];
#pragma unroll
    for (int j = 0; j < 32; ++j) v[j] = 0.f;
    for (int t = 0; t < TTIME; ++t) {
        int slice = t * BB + b;
        const float* yr = y + ((size_t)slice * C + ch) * NPOS + w * 32;
        unsigned int mw = 0;
#pragma unroll
        for (int q4 = 0; q4 < 8; ++q4) {
            float4 yv = *(const float4*)(yr + q4 * 4);
            float ya[4] = {yv.x, yv.y, yv.z, yv.w};
#pragma unroll
            for (int j = 0; j < 4; ++j) {
                int jj = q4 * 4 + j;
                float vn = v[jj] + (ya[j] - v[jj]) * 0.5f;
                int sp = (vn - vth) >= 0.0f;
                mw |= ((unsigned int)sp) << jj;
                v[jj] = sp ? 0.f : vn;
            }
        }
        mask[((size_t)slice * C + ch) * 64 + w] = mw;
    }
}

// ---------------- kv popcount ----------------
__global__ __launch_bounds__(256) void kv_kern(
    const unsigned int* __restrict__ km_g, const unsigned int* __restrict__ vm_g,
    int* __restrict__ kv_g)
{
    int blk = blockIdx.x;
    int h = blk & 7;
    int tb = blk >> 3;
    __shared__ unsigned int km[32][65], vm[32][65];
    int tid = threadIdx.x;
#pragma unroll
    for (int i = 0; i < 8; ++i) {
        int idx = i * 256 + tid;
        int d = idx >> 6, w = idx & 63;
        size_t rb = ((size_t)tb * C + h * 32 + d) * 64 + w;
        km[d][w] = km_g[rb];
        vm[d][w] = vm_g[rb];
    }
    __syncthreads();
#pragma unroll
    for (int k = 0; k < 4; ++k) {
        int p = k * 256 + tid;
        int d = p >> 5, e = p & 31;
        int s = 0;
#pragma unroll
        for (int w = 0; w < 64; ++w)
            s += __popc(km[d][w] & vm[e][w]);
        kv_g[(size_t)blk * 1024 + p] = s;
    }
}

// ---------------- attention + attn-LIF -> bit mask ----------------
__global__ __launch_bounds__(256) void attn_kern(
    const unsigned int* __restrict__ qm_g, const int* __restrict__ kv_g,
    unsigned int* __restrict__ amask)
{
    int blk = blockIdx.x;
    int chunk = blk & 7;
    int bh = blk >> 3;
    int h = bh & 7, b = bh >> 3;
    int tid = threadIdx.x;
    __shared__ int kvs[1024];
    __shared__ unsigned int qw[32][8];
    float v[32];
#pragma unroll
    for (int e = 0; e < 32; ++e) v[e] = 0.f;
    for (int t = 0; t < TTIME; ++t) {
        int tb = t * BB + b;
        __syncthreads();
#pragma unroll
        for (int k = 0; k < 4; ++k)
            kvs[k * 256 + tid] = kv_g[((size_t)tb * 8 + h) * 1024 + k * 256 + tid];
        {
            int d = tid >> 3, wi = tid & 7;
            qw[d][wi] = qm_g[((size_t)tb * C + h * 32 + d) * 64 + chunk * 8 + wi];
        }
        __syncthreads();
        int a[32];
#pragma unroll
        for (int e = 0; e < 32; ++e) a[e] = 0;
        int wsel = tid >> 5, bitp = tid & 31;
        for (int d = 0; d < 32; ++d) {
            if ((qw[d][wsel] >> bitp) & 1u) {
                const int* kr = &kvs[d * 32];
#pragma unroll
                for (int e = 0; e < 32; ++e) a[e] += kr[e];
            }
        }
#pragma unroll
        for (int e = 0; e < 32; ++e) {
            float f = (float)a[e] * 0.125f;
            v[e] = v[e] + (f - v[e]) * 0.5f;
            int sp = (v[e] - 0.5f) >= 0.0f;
            unsigned long long bb = __ballot(sp);
            if ((tid & 63) == 0) {
                int ch = h * 32 + e;
                unsigned long long* dst = (unsigned long long*)amask
                    + ((size_t)tb * C + ch) * 32 + chunk * 4 + (tid >> 6);
                *dst = bb;
            }
            if (sp) v[e] = 0.f;
        }
    }
}

extern "C" void kernel_launch(void* const* d_in, const int* in_sizes, int n_in,
                              void* d_out, int out_size, void* d_ws, size_t ws_size,
                              hipStream_t stream) {
    const float* q   = (const float*)d_in[0];
    const float* k_  = (const float*)d_in[1];
    const float* w1g = (const float*)d_in[2];
    const float* bn1 = (const float*)d_in[3];
    const float* w3g = (const float*)d_in[4];
    const float* w2g = (const float*)d_in[5];
    const float* bn2 = (const float*)d_in[6];
    const float* bno = (const float*)d_in[7];

    float* prm = (float*)d_ws;                                  // 6*132096 f32
    unsigned short* frags = (unsigned short*)(prm + 6 * PRM_STRIDE);  // 12*196608 bf16
    float* tsb  = (float*)(frags + 12 * FRAG_ELEMS);            // 16777216 f32
    float* buf1 = tsb + 16777216;                               // 16777216 f32
    unsigned int* qmask = (unsigned int*)(buf1 + 16777216);     // 524288 u32 each
    unsigned int* kmask = qmask + 524288;
    unsigned int* vmask = kmask + 524288;
    int* kvb = (int*)(vmask + 524288);                          // 262144 int
    unsigned int* amask = (unsigned int*)buf1;                  // overlay (buf1 dead)

    prep_kern<<<6, 256, 0, stream>>>(w1g, bn1, w3g, w2g, bn2, bno, prm);
    prep2_kern<<<12, 256, 0, stream>>>(prm, frags);

#define FRAG(i, which) (frags + (size_t)((i) * 2 + (which)) * FRAG_ELEMS)
#define PRMI(i) (prm + (size_t)(i) * PRM_STRIDE)

    // q branch
    gemmA_mfma<0><<<1024, 256, 0, stream>>>(q, nullptr, tsb, FRAG(0, 0));
    gemmB_mfma<<<1024, 256, 0, stream>>>(tsb, buf1, FRAG(0, 1), PRMI(0));
    lif_kern<<<512, 256, 0, stream>>>(buf1, qmask, 1.0f);
    // k branch
    gemmA_mfma<0><<<1024, 256, 0, stream>>>(k_, nullptr, tsb, FRAG(1, 0));
    gemmB_mfma<<<1024, 256, 0, stream>>>(tsb, buf1, FRAG(1, 1), PRMI(1));
    gemmA_mfma<0><<<1024, 256, 0, stream>>>(buf1, nullptr, tsb, FRAG(2, 0));
    gemmB_mfma<<<1024, 256, 0, stream>>>(tsb, buf1, FRAG(2, 1), PRMI(2));
    lif_kern<<<512, 256, 0, stream>>>(buf1, kmask, 1.0f);
    // v branch
    gemmA_mfma<0><<<1024, 256, 0, stream>>>(k_, nullptr, tsb, FRAG(3, 0));
    gemmB_mfma<<<1024, 256, 0, stream>>>(tsb, buf1, FRAG(3, 1), PRMI(3));
    gemmA_mfma<0><<<1024, 256, 0, stream>>>(buf1, nullptr, tsb, FRAG(4, 0));
    gemmB_mfma<<<1024, 256, 0, stream>>>(tsb, buf1, FRAG(4, 1), PRMI(4));
    lif_kern<<<512, 256, 0, stream>>>(buf1, vmask, 1.0f);

    kv_kern<<<256, 256, 0, stream>>>(kmask, vmask, kvb);
    attn_kern<<<512, 256, 0, stream>>>(qmask, kvb, amask);

    // final conv: spike-input GEMM (exact 1-split, 3 products) then B
    gemmA_mfma<1><<<1024, 256, 0, stream>>>(nullptr, amask, tsb, FRAG(5, 0));
    gemmB_mfma<<<1024, 256, 0, stream>>>(tsb, (float*)d_out, FRAG(5, 1), PRMI(5));
}

// Round 4
// 1083.490 us; speedup vs baseline: 3.3989x; 1.3376x over previous
//
#include <hip/hip_runtime.h>

#define C 256
#define NPOS 2048
#define BB 8
#define TTIME 4
#define PRM_STRIDE 132096  // w1fT 65536 | w2fT 65536 | w3T 768 | bias 256
#define FRAG_ELEMS 196608  // 8 ks * 16 rt * 3 s * 64 lane * 8 j (bf16)

typedef float f32x4 __attribute__((ext_vector_type(4)));
typedef short short8 __attribute__((ext_vector_type(8)));
typedef unsigned int u32x4 __attribute__((ext_vector_type(4)));

static __device__ __forceinline__ unsigned short f2bf(float f) {
    unsigned int u = __float_as_uint(f);
    return (unsigned short)((u + 0x7FFFu + ((u >> 16) & 1u)) >> 16);
}
static __device__ __forceinline__ float bf2f(unsigned short b) {
    return __uint_as_float(((unsigned int)b) << 16);
}
static __device__ __forceinline__ void split3(float f, unsigned short& h,
                                              unsigned short& m, unsigned short& l) {
    h = f2bf(f);
    float r1 = f - bf2f(h);
    m = f2bf(r1);
    float r2 = r1 - bf2f(m);
    l = f2bf(r2);
}

// ---------------- PREP1: fold BN params into conv weights (f32) ----------------
__global__ __launch_bounds__(256) void prep_kern(
    const float* __restrict__ w1g, const float* __restrict__ bn1,
    const float* __restrict__ w3g, const float* __restrict__ w2g,
    const float* __restrict__ bn2, const float* __restrict__ bno,
    float* __restrict__ prm)
{
    int i = blockIdx.x;
    int tid = threadIdx.x;
    __shared__ float s1l[C], hcl[C], SGl[C];
    const float* b1 = bn1 + i * 4 * C;
    const float* b2 = bn2 + i * 4 * C;
    const float* bo = bno + i * 4 * C;
    float g1 = b1[tid], be1 = b1[C + tid], mu1 = b1[2 * C + tid], va1 = b1[3 * C + tid];
    float s1 = g1 / sqrtf(va1 + 1e-5f);
    float h1 = be1 - mu1 * s1;
    float g2 = b2[tid], be2 = b2[C + tid], mu2 = b2[2 * C + tid], va2 = b2[3 * C + tid];
    float s2 = g2 / sqrtf(va2 + 1e-5f);
    float h2 = be2 - mu2 * s2;
    float go = bo[tid], beo = bo[C + tid], muo = bo[2 * C + tid], vao = bo[3 * C + tid];
    float so = go / sqrtf(vao + 1e-5f);
    float ho = beo - muo * so;
    float SG = so * s2;
    float SH = so * h2 + ho;
    const float* w3i = w3g + i * C * 3;
    float w3s = w3i[tid * 3 + 0] + w3i[tid * 3 + 1] + w3i[tid * 3 + 2];
    s1l[tid] = s1; hcl[tid] = w3s * h1; SGl[tid] = SG;
    __syncthreads();
    float* prmi = prm + (size_t)i * PRM_STRIDE;
    const float* w1i = w1g + (size_t)i * C * C;
    const float* w2i = w2g + (size_t)i * C * C;
    for (int k = 0; k < C; ++k)
        prmi[tid * C + k] = s1l[k] * w1i[k * C + tid];
    for (int k = 0; k < C; ++k)
        prmi[65536 + tid * C + k] = SGl[k] * w2i[k * C + tid];
    for (int j = 0; j < 3; ++j)
        prmi[131072 + j * C + tid] = w3i[tid * 3 + j];
    float dot = 0.f;
    for (int k = 0; k < C; ++k)
        dot = fmaf(w2i[tid * C + k], hcl[k], dot);
    prmi[131840 + tid] = SG * dot + SH;
}

// ---------------- PREP2: build bf16x3 MFMA A-fragments ----------------
// frag layout: ((((ks*16 + rt)*3 + s)*64 + lane)*8 + j)
// lane l holds A[m = rt*16 + (l&15)][k = ks*32 + (l>>4)*8 + j]
__global__ __launch_bounds__(256) void prep2_kern(
    const float* __restrict__ prm, unsigned short* __restrict__ frags)
{
    int b = blockIdx.x;           // 12 = 6 convs x 2 matrices
    int i = b >> 1, which = b & 1;
    const float* src = prm + (size_t)i * PRM_STRIDE + which * 65536;  // wT[k*256+m]
    unsigned short* dst = frags + (size_t)b * FRAG_ELEMS;
    for (int e = threadIdx.x; e < 65536; e += 256) {
        int m = e & 255, k = e >> 8;
        float w = src[k * 256 + m];
        unsigned short h, mi, lo;
        split3(w, h, mi, lo);
        int ks = k >> 5, kin = k & 31;
        int rt = m >> 4;
        int lane = (m & 15) | (((kin >> 3) & 3) << 4);
        int j = kin & 7;
        size_t base = ((size_t)(ks * 16 + rt) * 3) * 64 * 8 + lane * 8 + j;
        dst[base] = h;
        dst[base + 512] = mi;
        dst[base + 1024] = lo;
    }
}

// ---------------- MFMA GEMM A: uT[pos][m] = W1f * x ----------------
// LDS per plane: [col 0..63] x 16 chunks of 16B; chunk index = oct ^ (col&7)
// IN_MODE: 0 = STD f32 [c][pos], 1 = TRS f32 [pos][c], 2 = SPIKE bitmask
template<int IN_MODE>
__global__ __launch_bounds__(256, 3) void gemmA_mfma(
    const float* __restrict__ x, const unsigned int* __restrict__ xmask,
    float* __restrict__ uT, const unsigned short* __restrict__ frag)
{
    __shared__ __align__(16) unsigned int pl[(IN_MODE == 2 ? 1 : 3) * 4096];
    int tid = threadIdx.x;
    int ctile = blockIdx.x & 31;
    int slice = blockIdx.x >> 5;
    int ct0 = ctile * 64;
    int col = tid & 63, q = tid >> 6;
    int lane = col, wv = q;
    f32x4 acc[4][4];
#pragma unroll
    for (int a = 0; a < 4; ++a)
#pragma unroll
        for (int b = 0; b < 4; ++b) acc[a][b] = (f32x4)0.f;
    const short8* Ab = (const short8*)frag;
    const int PA[6] = {0, 0, 1, 0, 2, 1};
    const int PB[6] = {0, 1, 0, 2, 0, 1};

    for (int phase = 0; phase < 2; ++phase) {
        if (phase) __syncthreads();
        // ---- stage 128 k (channels) x 64 cols ----
#pragma unroll
        for (int i = 0; i < 4; ++i) {
            int oct = q * 4 + i;
            int c0 = phase * 128 + oct * 8;
            char* wb = (char*)pl + col * 256 + (((oct ^ (col & 7)) & 15) << 4);
            if (IN_MODE == 2) {
                const unsigned int* mg = xmask + (size_t)slice * C * 64 + ((ct0 + col) >> 5);
                int bitp = col & 31;
                u32x4 hp;
#pragma unroll
                for (int j2 = 0; j2 < 4; ++j2) {
                    unsigned int b0 = (mg[(c0 + 2 * j2) * 64] >> bitp) & 1u;
                    unsigned int b1 = (mg[(c0 + 2 * j2 + 1) * 64] >> bitp) & 1u;
                    hp[j2] = (b0 ? 0x3F80u : 0u) | ((b1 ? 0x3F80u : 0u) << 16);
                }
                *(u32x4*)wb = hp;
            } else {
                float xv[8];
                if (IN_MODE == 0) {
                    const float* xg = x + (size_t)slice * C * NPOS + ct0 + col;
#pragma unroll
                    for (int j = 0; j < 8; ++j)
                        xv[j] = xg[(size_t)(c0 + j) * NPOS];
                } else {
                    const float4* rp = (const float4*)(x + ((size_t)slice * NPOS + ct0 + col) * C + c0);
                    float4 a = rp[0], b = rp[1];
                    xv[0] = a.x; xv[1] = a.y; xv[2] = a.z; xv[3] = a.w;
                    xv[4] = b.x; xv[5] = b.y; xv[6] = b.z; xv[7] = b.w;
                }
                unsigned short h[8], m[8], l[8];
#pragma unroll
                for (int j = 0; j < 8; ++j) split3(xv[j], h[j], m[j], l[j]);
                u32x4 hp, mp, lp;
#pragma unroll
                for (int j2 = 0; j2 < 4; ++j2) {
                    hp[j2] = (unsigned int)h[2 * j2] | ((unsigned int)h[2 * j2 + 1] << 16);
                    mp[j2] = (unsigned int)m[2 * j2] | ((unsigned int)m[2 * j2 + 1] << 16);
                    lp[j2] = (unsigned int)l[2 * j2] | ((unsigned int)l[2 * j2 + 1] << 16);
                }
                *(u32x4*)wb = hp;
                *(u32x4*)(wb + 16384) = mp;
                *(u32x4*)(wb + 32768) = lp;
            }
        }
        __syncthreads();
        // ---- MFMA over this K-phase ----
#pragma unroll
        for (int ksl = 0; ksl < 4; ++ksl) {
            int ks = phase * 4 + ksl;
            short8 A[4][3];
#pragma unroll
            for (int rt = 0; rt < 4; ++rt)
#pragma unroll
                for (int s = 0; s < 3; ++s)
                    A[rt][s] = Ab[(size_t)((ks * 16 + wv * 4 + rt) * 3 + s) * 64 + lane];
            int cb[4], ch[4];
#pragma unroll
            for (int ct = 0; ct < 4; ++ct) {
                int colb = ct * 16 + (lane & 15);
                cb[ct] = colb * 256;
                ch[ct] = (((ksl * 4 + (lane >> 4)) ^ (colb & 7)) & 15) << 4;
            }
            if (IN_MODE == 2) {
                short8 B[4];
#pragma unroll
                for (int ct = 0; ct < 4; ++ct)
                    B[ct] = *(const short8*)((const char*)pl + cb[ct] + ch[ct]);
                __builtin_amdgcn_s_setprio(1);
#pragma unroll
                for (int p = 0; p < 3; ++p)
#pragma unroll
                    for (int rt = 0; rt < 4; ++rt)
#pragma unroll
                        for (int ct = 0; ct < 4; ++ct)
                            acc[rt][ct] = __builtin_amdgcn_mfma_f32_16x16x32_bf16(
                                A[rt][p], B[ct], acc[rt][ct], 0, 0, 0);
                __builtin_amdgcn_s_setprio(0);
            } else {
                short8 B[4][3];
#pragma unroll
                for (int ct = 0; ct < 4; ++ct) {
                    B[ct][0] = *(const short8*)((const char*)pl + cb[ct] + ch[ct]);
                    B[ct][1] = *(const short8*)((const char*)pl + 16384 + cb[ct] + ch[ct]);
                    B[ct][2] = *(const short8*)((const char*)pl + 32768 + cb[ct] + ch[ct]);
                }
                __builtin_amdgcn_s_setprio(1);
#pragma unroll
                for (int p = 0; p < 6; ++p)
#pragma unroll
                    for (int rt = 0; rt < 4; ++rt)
#pragma unroll
                        for (int ct = 0; ct < 4; ++ct)
                            acc[rt][ct] = __builtin_amdgcn_mfma_f32_16x16x32_bf16(
                                A[rt][PA[p]], B[ct][PB[p]], acc[rt][ct], 0, 0, 0);
                __builtin_amdgcn_s_setprio(0);
            }
        }
    }
    // ---- epilogue: uT[pos][m], contiguous float4 per (rt,ct) ----
    int pr = lane & 15, rg = lane >> 4;
    float* uS = uT + (size_t)slice * NPOS * C;
#pragma unroll
    for (int rt = 0; rt < 4; ++rt) {
        int m0 = wv * 64 + rt * 16 + rg * 4;
#pragma unroll
        for (int ct = 0; ct < 4; ++ct) {
            int pos = ct0 + ct * 16 + pr;
            *(f32x4*)(uS + (size_t)pos * C + m0) = acc[rt][ct];
        }
    }
}

// ---------------- MFMA GEMM B: y = W2f * depthwise3(uT) + bias ----------------
// OUT_T: 1 = transposed yT[pos][c], 0 = standard y[c][pos]
template<int OUT_T>
__global__ __launch_bounds__(256, 3) void gemmB_mfma(
    const float* __restrict__ uT, float* __restrict__ y,
    const unsigned short* __restrict__ frag, const float* __restrict__ prmi)
{
    __shared__ __align__(16) unsigned int pl[3 * 4096];
    int tid = threadIdx.x;
    int ctile = blockIdx.x & 31;
    int slice = blockIdx.x >> 5;
    int ct0 = ctile * 64;
    int col = tid & 63, q = tid >> 6;
    int lane = col, wv = q;
    const float* w3p = prmi + 131072;
    const float* uS = uT + (size_t)slice * NPOS * C;
    int gc = ct0 + col;
    f32x4 acc[4][4];
#pragma unroll
    for (int a = 0; a < 4; ++a)
#pragma unroll
        for (int b = 0; b < 4; ++b) acc[a][b] = (f32x4)0.f;
    const short8* Ab = (const short8*)frag;
    const int PA[6] = {0, 0, 1, 0, 2, 1};
    const int PB[6] = {0, 1, 0, 2, 0, 1};

    for (int phase = 0; phase < 2; ++phase) {
        if (phase) __syncthreads();
#pragma unroll
        for (int i = 0; i < 4; ++i) {
            int oct = q * 4 + i;
            int c0 = phase * 128 + oct * 8;
            float uc[8], ul[8], ur[8];
            {
                const float4* pc = (const float4*)(uS + (size_t)gc * C + c0);
                float4 a = pc[0], b = pc[1];
                uc[0] = a.x; uc[1] = a.y; uc[2] = a.z; uc[3] = a.w;
                uc[4] = b.x; uc[5] = b.y; uc[6] = b.z; uc[7] = b.w;
            }
            if (gc > 0) {
                const float4* pp = (const float4*)(uS + (size_t)(gc - 1) * C + c0);
                float4 a = pp[0], b = pp[1];
                ul[0] = a.x; ul[1] = a.y; ul[2] = a.z; ul[3] = a.w;
                ul[4] = b.x; ul[5] = b.y; ul[6] = b.z; ul[7] = b.w;
            } else {
#pragma unroll
                for (int j = 0; j < 8; ++j) ul[j] = 0.f;
            }
            if (gc < NPOS - 1) {
                const float4* pn = (const float4*)(uS + (size_t)(gc + 1) * C + c0);
                float4 a = pn[0], b = pn[1];
                ur[0] = a.x; ur[1] = a.y; ur[2] = a.z; ur[3] = a.w;
                ur[4] = b.x; ur[5] = b.y; ur[6] = b.z; ur[7] = b.w;
            } else {
#pragma unroll
                for (int j = 0; j < 8; ++j) ur[j] = 0.f;
            }
            unsigned short h[8], m[8], l[8];
#pragma unroll
            for (int j = 0; j < 8; ++j) {
                int c = c0 + j;
                float t = w3p[c] * ul[j] + w3p[256 + c] * uc[j] + w3p[512 + c] * ur[j];
                split3(t, h[j], m[j], l[j]);
            }
            u32x4 hp, mp, lp;
#pragma unroll
            for (int j2 = 0; j2 < 4; ++j2) {
                hp[j2] = (unsigned int)h[2 * j2] | ((unsigned int)h[2 * j2 + 1] << 16);
                mp[j2] = (unsigned int)m[2 * j2] | ((unsigned int)m[2 * j2 + 1] << 16);
                lp[j2] = (unsigned int)l[2 * j2] | ((unsigned int)l[2 * j2 + 1] << 16);
            }
            char* wb = (char*)pl + col * 256 + (((oct ^ (col & 7)) & 15) << 4);
            *(u32x4*)wb = hp;
            *(u32x4*)(wb + 16384) = mp;
            *(u32x4*)(wb + 32768) = lp;
        }
        __syncthreads();
#pragma unroll
        for (int ksl = 0; ksl < 4; ++ksl) {
            int ks = phase * 4 + ksl;
            short8 A[4][3];
#pragma unroll
            for (int rt = 0; rt < 4; ++rt)
#pragma unroll
                for (int s = 0; s < 3; ++s)
                    A[rt][s] = Ab[(size_t)((ks * 16 + wv * 4 + rt) * 3 + s) * 64 + lane];
            short8 B[4][3];
#pragma unroll
            for (int ct = 0; ct < 4; ++ct) {
                int colb = ct * 16 + (lane & 15);
                int cb = colb * 256;
                int ch = (((ksl * 4 + (lane >> 4)) ^ (colb & 7)) & 15) << 4;
                B[ct][0] = *(const short8*)((const char*)pl + cb + ch);
                B[ct][1] = *(const short8*)((const char*)pl + 16384 + cb + ch);
                B[ct][2] = *(const short8*)((const char*)pl + 32768 + cb + ch);
            }
            __builtin_amdgcn_s_setprio(1);
#pragma unroll
            for (int p = 0; p < 6; ++p)
#pragma unroll
                for (int rt = 0; rt < 4; ++rt)
#pragma unroll
                    for (int ct = 0; ct < 4; ++ct)
                        acc[rt][ct] = __builtin_amdgcn_mfma_f32_16x16x32_bf16(
                            A[rt][PA[p]], B[ct][PB[p]], acc[rt][ct], 0, 0, 0);
            __builtin_amdgcn_s_setprio(0);
        }
    }
    const float* bs = prmi + 131840;
    int pr = lane & 15, rg = lane >> 4;
    float* yS = y + (size_t)slice * NPOS * C;
#pragma unroll
    for (int rt = 0; rt < 4; ++rt) {
        int m0 = wv * 64 + rt * 16 + rg * 4;
#pragma unroll
        for (int ct = 0; ct < 4; ++ct) {
            int pos = ct0 + ct * 16 + pr;
            if (OUT_T) {
                f32x4 o;
#pragma unroll
                for (int r = 0; r < 4; ++r) o[r] = acc[rt][ct][r] + bs[m0 + r];
                *(f32x4*)(yS + (size_t)pos * C + m0) = o;
            } else {
#pragma unroll
                for (int r = 0; r < 4; ++r)
                    yS[(size_t)(m0 + r) * NPOS + pos] = acc[rt][ct][r] + bs[m0 + r];
            }
        }
    }
}

// ---------------- LIF + bitpack over T timesteps (reads yT[pos][c]) ----------------
__global__ __launch_bounds__(256) void lif_kern(
    const float* __restrict__ yT, unsigned int* __restrict__ mask, float vth)
{
    int g = blockIdx.x * 256 + threadIdx.x;   // 131072 = 8b x 64w x 256ch
    int ch = g & 255;
    int w = (g >> 8) & 63;
    int b = g >> 14;
    float v[32];
#pragma unroll
    for (int j = 0; j < 32; ++j) v[j] = 0.f;
    for (int t = 0; t < TTIME; ++t) {
        int slice = t * BB + b;
        const float* yr = yT + ((size_t)slice * NPOS + w * 32) * C + ch;
        unsigned int mw = 0;
#pragma unroll
        for (int j = 0; j < 32; ++j) {
            float yy = yr[(size_t)j * C];
            float vn = v[j] + (yy - v[j]) * 0.5f;
            int sp = (vn - vth) >= 0.0f;
            mw |= ((unsigned int)sp) << j;
            v[j] = sp ? 0.f : vn;
        }
        mask[((size_t)slice * C + ch) * 64 + w] = mw;
    }
}

// ---------------- kv popcount ----------------
__global__ __launch_bounds__(256) void kv_kern(
    const unsigned int* __restrict__ km_g, const unsigned int* __restrict__ vm_g,
    int* __restrict__ kv_g)
{
    int blk = blockIdx.x;
    int h = blk & 7;
    int tb = blk >> 3;
    __shared__ unsigned int km[32][65], vm[32][65];
    int tid = threadIdx.x;
#pragma unroll
    for (int i = 0; i < 8; ++i) {
        int idx = i * 256 + tid;
        int d = idx >> 6, w = idx & 63;
        size_t rb = ((size_t)tb * C + h * 32 + d) * 64 + w;
        km[d][w] = km_g[rb];
        vm[d][w] = vm_g[rb];
    }
    __syncthreads();
#pragma unroll
    for (int k = 0; k < 4; ++k) {
        int p = k * 256 + tid;
        int d = p >> 5, e = p & 31;
        int s = 0;
#pragma unroll
        for (int w = 0; w < 64; ++w)
            s += __popc(km[d][w] & vm[e][w]);
        kv_g[(size_t)blk * 1024 + p] = s;
    }
}

// ---------------- attention + attn-LIF -> bit mask ----------------
__global__ __launch_bounds__(256) void attn_kern(
    const unsigned int* __restrict__ qm_g, const int* __restrict__ kv_g,
    unsigned int* __restrict__ amask)
{
    int blk = blockIdx.x;
    int chunk = blk & 7;
    int bh = blk >> 3;
    int h = bh & 7, b = bh >> 3;
    int tid = threadIdx.x;
    __shared__ int kvs[1024];
    __shared__ unsigned int qw[32][8];
    float v[32];
#pragma unroll
    for (int e = 0; e < 32; ++e) v[e] = 0.f;
    for (int t = 0; t < TTIME; ++t) {
        int tb = t * BB + b;
        __syncthreads();
#pragma unroll
        for (int k = 0; k < 4; ++k)
            kvs[k * 256 + tid] = kv_g[((size_t)tb * 8 + h) * 1024 + k * 256 + tid];
        {
            int d = tid >> 3, wi = tid & 7;
            qw[d][wi] = qm_g[((size_t)tb * C + h * 32 + d) * 64 + chunk * 8 + wi];
        }
        __syncthreads();
        int a[32];
#pragma unroll
        for (int e = 0; e < 32; ++e) a[e] = 0;
        int wsel = tid >> 5, bitp = tid & 31;
        for (int d = 0; d < 32; ++d) {
            if ((qw[d][wsel] >> bitp) & 1u) {
                const int* kr = &kvs[d * 32];
#pragma unroll
                for (int e = 0; e < 32; ++e) a[e] += kr[e];
            }
        }
#pragma unroll
        for (int e = 0; e < 32; ++e) {
            float f = (float)a[e] * 0.125f;
            v[e] = v[e] + (f - v[e]) * 0.5f;
            int sp = (v[e] - 0.5f) >= 0.0f;
            unsigned long long bb = __ballot(sp);
            if ((tid & 63) == 0) {
                int ch = h * 32 + e;
                unsigned long long* dst = (unsigned long long*)amask
                    + ((size_t)tb * C + ch) * 32 + chunk * 4 + (tid >> 6);
                *dst = bb;
            }
            if (sp) v[e] = 0.f;
        }
    }
}

extern "C" void kernel_launch(void* const* d_in, const int* in_sizes, int n_in,
                              void* d_out, int out_size, void* d_ws, size_t ws_size,
                              hipStream_t stream) {
    const float* q   = (const float*)d_in[0];
    const float* k_  = (const float*)d_in[1];
    const float* w1g = (const float*)d_in[2];
    const float* bn1 = (const float*)d_in[3];
    const float* w3g = (const float*)d_in[4];
    const float* w2g = (const float*)d_in[5];
    const float* bn2 = (const float*)d_in[6];
    const float* bno = (const float*)d_in[7];

    float* prm = (float*)d_ws;                                        // 792576 f32
    unsigned short* frags = (unsigned short*)(prm + 6 * PRM_STRIDE);  // 12*196608 bf16
    float* uT = (float*)(frags + 12 * FRAG_ELEMS);                    // 16777216 f32
    float* yT = uT + 16777216;                                        // 16777216 f32
    unsigned int* qmask = (unsigned int*)(yT + 16777216);             // 524288 u32 each
    unsigned int* kmask = qmask + 524288;
    unsigned int* vmask = kmask + 524288;
    int* kvb = (int*)(vmask + 524288);                                // 262144 i32
    unsigned int* amask = (unsigned int*)(kvb + 262144);              // 524288 u32

    prep_kern<<<6, 256, 0, stream>>>(w1g, bn1, w3g, w2g, bn2, bno, prm);
    prep2_kern<<<12, 256, 0, stream>>>(prm, frags);

#define FRAG(i, which) (frags + (size_t)((i) * 2 + (which)) * FRAG_ELEMS)
#define PRMI(i) (prm + (size_t)(i) * PRM_STRIDE)

    // q branch: conv0 -> LIF -> qmask
    gemmA_mfma<0><<<1024, 256, 0, stream>>>(q, nullptr, uT, FRAG(0, 0));
    gemmB_mfma<1><<<1024, 256, 0, stream>>>(uT, yT, FRAG(0, 1), PRMI(0));
    lif_kern<<<512, 256, 0, stream>>>(yT, qmask, 1.0f);
    // k branch: conv1 -> conv2 -> LIF -> kmask
    gemmA_mfma<0><<<1024, 256, 0, stream>>>(k_, nullptr, uT, FRAG(1, 0));
    gemmB_mfma<1><<<1024, 256, 0, stream>>>(uT, yT, FRAG(1, 1), PRMI(1));
    gemmA_mfma<1><<<1024, 256, 0, stream>>>(yT, nullptr, uT, FRAG(2, 0));
    gemmB_mfma<1><<<1024, 256, 0, stream>>>(uT, yT, FRAG(2, 1), PRMI(2));
    lif_kern<<<512, 256, 0, stream>>>(yT, kmask, 1.0f);
    // v branch: conv3 -> conv4 -> LIF -> vmask
    gemmA_mfma<0><<<1024, 256, 0, stream>>>(k_, nullptr, uT, FRAG(3, 0));
    gemmB_mfma<1><<<1024, 256, 0, stream>>>(uT, yT, FRAG(3, 1), PRMI(3));
    gemmA_mfma<1><<<1024, 256, 0, stream>>>(yT, nullptr, uT, FRAG(4, 0));
    gemmB_mfma<1><<<1024, 256, 0, stream>>>(uT, yT, FRAG(4, 1), PRMI(4));
    lif_kern<<<512, 256, 0, stream>>>(yT, vmask, 1.0f);

    kv_kern<<<256, 256, 0, stream>>>(kmask, vmask, kvb);
    attn_kern<<<512, 256, 0, stream>>>(qmask, kvb, amask);

    // final conv5: spike-input GEMM then standard-layout output
    gemmA_mfma<2><<<1024, 256, 0, stream>>>(nullptr, amask, uT, FRAG(5, 0));
    gemmB_mfma<0><<<1024, 256, 0, stream>>>(uT, (float*)d_out, FRAG(5, 1), PRMI(5));
}

// Round 5
// 1048.687 us; speedup vs baseline: 3.5117x; 1.0332x over previous
//
#include <hip/hip_runtime.h>

#define C 256
#define NPOS 2048
#define BB 8
#define TTIME 4
#define PRM_STRIDE 132096  // w1fT 65536 | w2fT 65536 | w3T 768 | bias 256
#define FRAG_ELEMS 196608  // 8 ks * 16 mt * 3 s * 64 lane * 8 j (bf16)

typedef float f32x4 __attribute__((ext_vector_type(4)));
typedef short short8 __attribute__((ext_vector_type(8)));
typedef unsigned int u32x4 __attribute__((ext_vector_type(4)));

static __device__ __forceinline__ unsigned short f2bf(float f) {
    unsigned int u = __float_as_uint(f);
    return (unsigned short)((u + 0x7FFFu + ((u >> 16) & 1u)) >> 16);
}
static __device__ __forceinline__ float bf2f(unsigned short b) {
    return __uint_as_float(((unsigned int)b) << 16);
}
static __device__ __forceinline__ void split3(float f, unsigned short& h,
                                              unsigned short& m, unsigned short& l) {
    h = f2bf(f);
    float r1 = f - bf2f(h);
    m = f2bf(r1);
    float r2 = r1 - bf2f(m);
    l = f2bf(r2);
}
static __device__ __forceinline__ unsigned long long pack4(const unsigned short* a) {
    return (unsigned long long)a[0] | ((unsigned long long)a[1] << 16)
         | ((unsigned long long)a[2] << 32) | ((unsigned long long)a[3] << 48);
}

// ---------------- PREP1: fold BN params into conv weights (f32) ----------------
__global__ __launch_bounds__(256) void prep_kern(
    const float* __restrict__ w1g, const float* __restrict__ bn1,
    const float* __restrict__ w3g, const float* __restrict__ w2g,
    const float* __restrict__ bn2, const float* __restrict__ bno,
    float* __restrict__ prm)
{
    int i = blockIdx.x;
    int tid = threadIdx.x;
    __shared__ float s1l[C], hcl[C], SGl[C];
    const float* b1 = bn1 + i * 4 * C;
    const float* b2 = bn2 + i * 4 * C;
    const float* bo = bno + i * 4 * C;
    float g1 = b1[tid], be1 = b1[C + tid], mu1 = b1[2 * C + tid], va1 = b1[3 * C + tid];
    float s1 = g1 / sqrtf(va1 + 1e-5f);
    float h1 = be1 - mu1 * s1;
    float g2 = b2[tid], be2 = b2[C + tid], mu2 = b2[2 * C + tid], va2 = b2[3 * C + tid];
    float s2 = g2 / sqrtf(va2 + 1e-5f);
    float h2 = be2 - mu2 * s2;
    float go = bo[tid], beo = bo[C + tid], muo = bo[2 * C + tid], vao = bo[3 * C + tid];
    float so = go / sqrtf(vao + 1e-5f);
    float ho = beo - muo * so;
    float SG = so * s2;
    float SH = so * h2 + ho;
    const float* w3i = w3g + i * C * 3;
    float w3s = w3i[tid * 3 + 0] + w3i[tid * 3 + 1] + w3i[tid * 3 + 2];
    s1l[tid] = s1; hcl[tid] = w3s * h1; SGl[tid] = SG;
    __syncthreads();
    float* prmi = prm + (size_t)i * PRM_STRIDE;
    const float* w1i = w1g + (size_t)i * C * C;
    const float* w2i = w2g + (size_t)i * C * C;
    for (int k = 0; k < C; ++k)
        prmi[tid * C + k] = s1l[k] * w1i[k * C + tid];
    for (int k = 0; k < C; ++k)
        prmi[65536 + tid * C + k] = SGl[k] * w2i[k * C + tid];
    for (int j = 0; j < 3; ++j)
        prmi[131072 + j * C + tid] = w3i[tid * 3 + j];
    float dot = 0.f;
    for (int k = 0; k < C; ++k)
        dot = fmaf(w2i[tid * C + k], hcl[k], dot);
    prmi[131840 + tid] = SG * dot + SH;
}

// ---------------- PREP2: build bf16x3 MFMA A-fragments ----------------
// frag layout: ((((ks*16 + mt)*3 + s)*64 + lane)*8 + j)
// lane l holds A[m = mt*16 + (l&15)][k = ks*32 + (l>>4)*8 + j]
__global__ __launch_bounds__(256) void prep2_kern(
    const float* __restrict__ prm, unsigned short* __restrict__ frags)
{
    int b = blockIdx.x;           // 12 = 6 convs x 2 matrices
    int i = b >> 1, which = b & 1;
    const float* src = prm + (size_t)i * PRM_STRIDE + which * 65536;  // wT[k*256+m]
    unsigned short* dst = frags + (size_t)b * FRAG_ELEMS;
    for (int e = threadIdx.x; e < 65536; e += 256) {
        int m = e & 255, k = e >> 8;
        float w = src[k * 256 + m];
        unsigned short h, mi, lo;
        split3(w, h, mi, lo);
        int ks = k >> 5, kin = k & 31;
        int mt = m >> 4;
        int lane = (m & 15) | (((kin >> 3) & 3) << 4);
        int j = kin & 7;
        size_t base = ((size_t)(ks * 16 + mt) * 3) * 64 * 8 + lane * 8 + j;
        dst[base] = h;
        dst[base + 512] = mi;
        dst[base + 1024] = lo;
    }
}

// ---------------- FUSED conv: y = W2f * dw3(W1f * x) + bias ----------------
// IN_MODE: 0 = STD f32 [c][pos], 1 = TRS f32 [pos][c], 2 = SPIKE bitmask
// OUT_T:   1 = transposed yT[pos][c], 0 = standard y[c][pos]
// LDS: x planes (80 cols x 128 k, 2 phases) @ 0/20480/40960 (61440 B total)
//      t planes (64 cols x 128 k, 2 phases) @ 0/16384/32768 (time-disjoint)
template<int IN_MODE, int OUT_T>
__global__ __launch_bounds__(256, 2) void conv_fused(
    const float* __restrict__ x, const unsigned int* __restrict__ xmask,
    float* __restrict__ y, const unsigned short* __restrict__ fragA,
    const unsigned short* __restrict__ fragB, const float* __restrict__ prmi)
{
    __shared__ __align__(16) char lds[61440];
    const int tid = threadIdx.x;
    const int lane = tid & 63, wv = tid >> 6;
    const int ctile = blockIdx.x & 31;
    const int slice = blockIdx.x >> 5;
    const int l0 = ctile * 64;
    const int lo4 = lane & 15, rg = lane >> 4;
    const int PA[6] = {0, 0, 1, 0, 2, 1};
    const int PB[6] = {0, 1, 0, 2, 0, 1};

    int mt[4];
#pragma unroll
    for (int rt = 0; rt < 4; ++rt) mt[rt] = wv * 2 + (rt & 1) + ((rt >> 1) << 3);

    f32x4 acc1[4][5];
#pragma unroll
    for (int a = 0; a < 4; ++a)
#pragma unroll
        for (int b = 0; b < 5; ++b) acc1[a][b] = (f32x4)0.f;

    const short8* Ab1 = (const short8*)fragA;

    // ================= STAGE 1: u = W1f * x  (acc1[rt][ct], 80 staged cols) ====
    for (int p = 0; p < 2; ++p) {
        // ---- stage x planes: 80 cols x 128 k ----
#pragma unroll
        for (int it = 0; it < 5; ++it) {
            int u = it * 256 + tid;          // 1280 units
            int col = u % 80;
            int oct = u / 80;                // 0..15
            int gpos = l0 - 8 + col;
            int kq = p * 128 + oct * 8;
            bool ok = (unsigned)gpos < (unsigned)NPOS;
            char* wb = lds + col * 256 + (((oct ^ (col & 7)) & 15) << 4);
            if (IN_MODE == 2) {
                u32x4 hp = (u32x4)0u;
                if (ok) {
                    const unsigned int* mg = xmask + (size_t)slice * C * 64 + (gpos >> 5);
                    int bitp = gpos & 31;
#pragma unroll
                    for (int j2 = 0; j2 < 4; ++j2) {
                        unsigned int b0 = (mg[(kq + 2 * j2) * 64] >> bitp) & 1u;
                        unsigned int b1 = (mg[(kq + 2 * j2 + 1) * 64] >> bitp) & 1u;
                        hp[j2] = (b0 ? 0x3F80u : 0u) | ((b1 ? 0x3F80u : 0u) << 16);
                    }
                }
                *(u32x4*)wb = hp;
            } else {
                float xv[8];
                if (ok) {
                    if (IN_MODE == 0) {
                        const float* xg = x + (size_t)slice * C * NPOS + gpos;
#pragma unroll
                        for (int j = 0; j < 8; ++j)
                            xv[j] = xg[(size_t)(kq + j) * NPOS];
                    } else {
                        const float4* rp = (const float4*)(x + ((size_t)slice * NPOS + gpos) * C + kq);
                        float4 a = rp[0], b = rp[1];
                        xv[0] = a.x; xv[1] = a.y; xv[2] = a.z; xv[3] = a.w;
                        xv[4] = b.x; xv[5] = b.y; xv[6] = b.z; xv[7] = b.w;
                    }
                } else {
#pragma unroll
                    for (int j = 0; j < 8; ++j) xv[j] = 0.f;
                }
                unsigned short h[8], m[8], l[8];
#pragma unroll
                for (int j = 0; j < 8; ++j) split3(xv[j], h[j], m[j], l[j]);
                u32x4 hp, mp, lp;
#pragma unroll
                for (int j2 = 0; j2 < 4; ++j2) {
                    hp[j2] = (unsigned int)h[2 * j2] | ((unsigned int)h[2 * j2 + 1] << 16);
                    mp[j2] = (unsigned int)m[2 * j2] | ((unsigned int)m[2 * j2 + 1] << 16);
                    lp[j2] = (unsigned int)l[2 * j2] | ((unsigned int)l[2 * j2 + 1] << 16);
                }
                *(u32x4*)wb = hp;
                *(u32x4*)(wb + 20480) = mp;
                *(u32x4*)(wb + 40960) = lp;
            }
        }
        __syncthreads();
        // ---- MFMA this K-phase: ks = p*4 .. p*4+3 ----
#pragma unroll
        for (int ksl = 0; ksl < 4; ++ksl) {
            int ks = p * 4 + ksl;
            int oct = ksl * 4 + rg;          // 0..15
            short8 A[4][3];
#pragma unroll
            for (int rt = 0; rt < 4; ++rt)
#pragma unroll
                for (int s = 0; s < (IN_MODE == 2 ? 3 : 3); ++s)
                    A[rt][s] = Ab1[(size_t)((ks * 16 + mt[rt]) * 3 + s) * 64 + lane];
            int ba[5];
#pragma unroll
            for (int ct = 0; ct < 5; ++ct) {
                int colb = ct * 16 + lo4;
                ba[ct] = colb * 256 + (((oct ^ (colb & 7)) & 15) << 4);
            }
            if (IN_MODE == 2) {
                short8 B[5];
#pragma unroll
                for (int ct = 0; ct < 5; ++ct)
                    B[ct] = *(const short8*)(lds + ba[ct]);
                __builtin_amdgcn_s_setprio(1);
#pragma unroll
                for (int pp = 0; pp < 3; ++pp)
#pragma unroll
                    for (int rt = 0; rt < 4; ++rt)
#pragma unroll
                        for (int ct = 0; ct < 5; ++ct)
                            acc1[rt][ct] = __builtin_amdgcn_mfma_f32_16x16x32_bf16(
                                A[rt][pp], B[ct], acc1[rt][ct], 0, 0, 0);
                __builtin_amdgcn_s_setprio(0);
            } else {
                short8 B[5][3];
#pragma unroll
                for (int ct = 0; ct < 5; ++ct) {
                    B[ct][0] = *(const short8*)(lds + ba[ct]);
                    B[ct][1] = *(const short8*)(lds + 20480 + ba[ct]);
                    B[ct][2] = *(const short8*)(lds + 40960 + ba[ct]);
                }
                __builtin_amdgcn_s_setprio(1);
#pragma unroll
                for (int pp = 0; pp < 6; ++pp)
#pragma unroll
                    for (int rt = 0; rt < 4; ++rt)
#pragma unroll
                        for (int ct = 0; ct < 5; ++ct)
                            acc1[rt][ct] = __builtin_amdgcn_mfma_f32_16x16x32_bf16(
                                A[rt][PA[pp]], B[ct][PB[pp]], acc1[rt][ct], 0, 0, 0);
                __builtin_amdgcn_s_setprio(0);
            }
        }
        __syncthreads();
    }

    // ================= STAGE 2: y = W2f * dw3(u) =================
    const float* w3p = prmi + 131072;
    const short8* Ab2 = (const short8*)fragB;
    f32x4 acc2[4][4];
#pragma unroll
    for (int a = 0; a < 4; ++a)
#pragma unroll
        for (int b = 0; b < 4; ++b) acc2[a][b] = (f32x4)0.f;

    for (int tp = 0; tp < 2; ++tp) {
        // ---- depthwise (register shuffles) + split3 + t-plane write ----
        // every wave writes its rt = tp*2+{0,1} tiles; together they cover k' 0..127
#pragma unroll
        for (int rr = 0; rr < 2; ++rr) {
            int rt = tp * 2 + rr;
            int RTB = mt[rt] << 4;
            float w3a[4], w3b[4], w3c[4];
#pragma unroll
            for (int r = 0; r < 4; ++r) {
                int m = RTB + rg * 4 + r;
                w3a[r] = w3p[m]; w3b[r] = w3p[256 + m]; w3c[r] = w3p[512 + m];
            }
            int k0 = (RTB & 127) + rg * 4;
#pragma unroll
            for (int ct = 0; ct < 5; ++ct) {
                int sc = ct * 16 + lo4;
                unsigned short th[4], tm_[4], tl_[4];
#pragma unroll
                for (int r = 0; r < 4; ++r) {
                    float cur = acc1[rt][ct][r];
                    float prevv = acc1[rt][ct > 0 ? ct - 1 : 0][r];
                    float nextv = acc1[rt][ct < 4 ? ct + 1 : 4][r];
                    float sL  = __shfl(cur, lane - 1);
                    float sL2 = __shfl(prevv, lane + 15);
                    float sR  = __shfl(cur, lane + 1);
                    float sR2 = __shfl(nextv, lane - 15);
                    float uL = lo4 ? sL : sL2;
                    float uR = (lo4 == 15) ? sR2 : sR;
                    float t = w3a[r] * uL + w3b[r] * cur + w3c[r] * uR;
                    split3(t, th[r], tm_[r], tl_[r]);
                }
                if (sc >= 8 && sc < 72) {
                    int oc = sc - 8;
                    int base = oc * 256 + ((((k0 >> 3) ^ (oc & 7)) & 15) << 4) + (k0 & 7) * 2;
                    *(unsigned long long*)(lds + base) = pack4(th);
                    *(unsigned long long*)(lds + 16384 + base) = pack4(tm_);
                    *(unsigned long long*)(lds + 32768 + base) = pack4(tl_);
                }
            }
        }
        __syncthreads();
        // ---- MFMA: ks = tp*4 .. tp*4+3 ----
#pragma unroll
        for (int ksl = 0; ksl < 4; ++ksl) {
            int ks = tp * 4 + ksl;
            int chunk = ksl * 4 + rg;        // 0..15
            short8 A[4][3];
#pragma unroll
            for (int rt = 0; rt < 4; ++rt)
#pragma unroll
                for (int s = 0; s < 3; ++s)
                    A[rt][s] = Ab2[(size_t)((ks * 16 + mt[rt]) * 3 + s) * 64 + lane];
            short8 B[4][3];
#pragma unroll
            for (int ct = 0; ct < 4; ++ct) {
                int oc = ct * 16 + lo4;
                int ba = oc * 256 + (((chunk ^ (oc & 7)) & 15) << 4);
                B[ct][0] = *(const short8*)(lds + ba);
                B[ct][1] = *(const short8*)(lds + 16384 + ba);
                B[ct][2] = *(const short8*)(lds + 32768 + ba);
            }
            __builtin_amdgcn_s_setprio(1);
#pragma unroll
            for (int pp = 0; pp < 6; ++pp)
#pragma unroll
                for (int rt = 0; rt < 4; ++rt)
#pragma unroll
                    for (int ct = 0; ct < 4; ++ct)
                        acc2[rt][ct] = __builtin_amdgcn_mfma_f32_16x16x32_bf16(
                            A[rt][PA[pp]], B[ct][PB[pp]], acc2[rt][ct], 0, 0, 0);
            __builtin_amdgcn_s_setprio(0);
        }
        if (tp == 0) __syncthreads();
    }

    // ================= epilogue =================
    const float* bs = prmi + 131840;
    float* yS = y + (size_t)slice * NPOS * C;
#pragma unroll
    for (int rt = 0; rt < 4; ++rt) {
        int m0 = (mt[rt] << 4) + rg * 4;
#pragma unroll
        for (int ct = 0; ct < 4; ++ct) {
            int pos = l0 + ct * 16 + lo4;
            if (OUT_T) {
                f32x4 o;
#pragma unroll
                for (int r = 0; r < 4; ++r) o[r] = acc2[rt][ct][r] + bs[m0 + r];
                *(f32x4*)(yS + (size_t)pos * C + m0) = o;
            } else {
#pragma unroll
                for (int r = 0; r < 4; ++r)
                    yS[(size_t)(m0 + r) * NPOS + pos] = acc2[rt][ct][r] + bs[m0 + r];
            }
        }
    }
}

// ---------------- LIF + bitpack over T timesteps (reads yT[pos][c]) ----------------
__global__ __launch_bounds__(256) void lif_kern(
    const float* __restrict__ yT, unsigned int* __restrict__ mask, float vth)
{
    int g = blockIdx.x * 256 + threadIdx.x;   // 131072 = 8b x 64w x 256ch
    int ch = g & 255;
    int w = (g >> 8) & 63;
    int b = g >> 14;
    float v[32];
#pragma unroll
    for (int j = 0; j < 32; ++j) v[j] = 0.f;
    for (int t = 0; t < TTIME; ++t) {
        int slice = t * BB + b;
        const float* yr = yT + ((size_t)slice * NPOS + w * 32) * C + ch;
        unsigned int mw = 0;
#pragma unroll
        for (int j = 0; j < 32; ++j) {
            float yy = yr[(size_t)j * C];
            float vn = v[j] + (yy - v[j]) * 0.5f;
            int sp = (vn - vth) >= 0.0f;
            mw |= ((unsigned int)sp) << j;
            v[j] = sp ? 0.f : vn;
        }
        mask[((size_t)slice * C + ch) * 64 + w] = mw;
    }
}

// ---------------- kv popcount ----------------
__global__ __launch_bounds__(256) void kv_kern(
    const unsigned int* __restrict__ km_g, const unsigned int* __restrict__ vm_g,
    int* __restrict__ kv_g)
{
    int blk = blockIdx.x;
    int h = blk & 7;
    int tb = blk >> 3;
    __shared__ unsigned int km[32][65], vm[32][65];
    int tid = threadIdx.x;
#pragma unroll
    for (int i = 0; i < 8; ++i) {
        int idx = i * 256 + tid;
        int d = idx >> 6, w = idx & 63;
        size_t rb = ((size_t)tb * C + h * 32 + d) * 64 + w;
        km[d][w] = km_g[rb];
        vm[d][w] = vm_g[rb];
    }
    __syncthreads();
#pragma unroll
    for (int k = 0; k < 4; ++k) {
        int p = k * 256 + tid;
        int d = p >> 5, e = p & 31;
        int s = 0;
#pragma unroll
        for (int w = 0; w < 64; ++w)
            s += __popc(km[d][w] & vm[e][w]);
        kv_g[(size_t)blk * 1024 + p] = s;
    }
}

// ---------------- attention + attn-LIF -> bit mask ----------------
__global__ __launch_bounds__(256) void attn_kern(
    const unsigned int* __restrict__ qm_g, const int* __restrict__ kv_g,
    unsigned int* __restrict__ amask)
{
    int blk = blockIdx.x;
    int chunk = blk & 7;
    int bh = blk >> 3;
    int h = bh & 7, b = bh >> 3;
    int tid = threadIdx.x;
    __shared__ int kvs[1024];
    __shared__ unsigned int qw[32][8];
    float v[32];
#pragma unroll
    for (int e = 0; e < 32; ++e) v[e] = 0.f;
    for (int t = 0; t < TTIME; ++t) {
        int tb = t * BB + b;
        __syncthreads();
#pragma unroll
        for (int k = 0; k < 4; ++k)
            kvs[k * 256 + tid] = kv_g[((size_t)tb * 8 + h) * 1024 + k * 256 + tid];
        {
            int d = tid >> 3, wi = tid & 7;
            qw[d][wi] = qm_g[((size_t)tb * C + h * 32 + d) * 64 + chunk * 8 + wi];
        }
        __syncthreads();
        int a[32];
#pragma unroll
        for (int e = 0; e < 32; ++e) a[e] = 0;
        int wsel = tid >> 5, bitp = tid & 31;
        for (int d = 0; d < 32; ++d) {
            if ((qw[d][wsel] >> bitp) & 1u) {
                const int* kr = &kvs[d * 32];
#pragma unroll
                for (int e = 0; e < 32; ++e) a[e] += kr[e];
            }
        }
#pragma unroll
        for (int e = 0; e < 32; ++e) {
            float f = (float)a[e] * 0.125f;
            v[e] = v[e] + (f - v[e]) * 0.5f;
            int sp = (v[e] - 0.5f) >= 0.0f;
            unsigned long long bb = __ballot(sp);
            if ((tid & 63) == 0) {
                int ch = h * 32 + e;
                unsigned long long* dst = (unsigned long long*)amask
                    + ((size_t)tb * C + ch) * 32 + chunk * 4 + (tid >> 6);
                *dst = bb;
            }
            if (sp) v[e] = 0.f;
        }
    }
}

extern "C" void kernel_launch(void* const* d_in, const int* in_sizes, int n_in,
                              void* d_out, int out_size, void* d_ws, size_t ws_size,
                              hipStream_t stream) {
    const float* q   = (const float*)d_in[0];
    const float* k_  = (const float*)d_in[1];
    const float* w1g = (const float*)d_in[2];
    const float* bn1 = (const float*)d_in[3];
    const float* w3g = (const float*)d_in[4];
    const float* w2g = (const float*)d_in[5];
    const float* bn2 = (const float*)d_in[6];
    const float* bno = (const float*)d_in[7];

    float* prm = (float*)d_ws;                                        // 792576 f32
    unsigned short* frags = (unsigned short*)(prm + 6 * PRM_STRIDE);  // 12*196608 bf16
    float* bufA = (float*)(frags + 12 * FRAG_ELEMS);                  // 16777216 f32
    float* bufB = bufA + 16777216;                                    // 16777216 f32
    unsigned int* qmask = (unsigned int*)(bufB + 16777216);           // 524288 u32 each
    unsigned int* kmask = qmask + 524288;
    unsigned int* vmask = kmask + 524288;
    int* kvb = (int*)(vmask + 524288);                                // 262144 i32
    unsigned int* amask = (unsigned int*)(kvb + 262144);              // 524288 u32

    prep_kern<<<6, 256, 0, stream>>>(w1g, bn1, w3g, w2g, bn2, bno, prm);
    prep2_kern<<<12, 256, 0, stream>>>(prm, frags);

#define FRAG(i, which) (frags + (size_t)((i) * 2 + (which)) * FRAG_ELEMS)
#define PRMI(i) (prm + (size_t)(i) * PRM_STRIDE)

    // q branch: conv0 -> LIF -> qmask
    conv_fused<0, 1><<<1024, 256, 0, stream>>>(q, nullptr, bufA, FRAG(0, 0), FRAG(0, 1), PRMI(0));
    lif_kern<<<512, 256, 0, stream>>>(bufA, qmask, 1.0f);
    // k branch: conv1 -> conv2 -> LIF -> kmask
    conv_fused<0, 1><<<1024, 256, 0, stream>>>(k_, nullptr, bufA, FRAG(1, 0), FRAG(1, 1), PRMI(1));
    conv_fused<1, 1><<<1024, 256, 0, stream>>>(bufA, nullptr, bufB, FRAG(2, 0), FRAG(2, 1), PRMI(2));
    lif_kern<<<512, 256, 0, stream>>>(bufB, kmask, 1.0f);
    // v branch: conv3 -> conv4 -> LIF -> vmask
    conv_fused<0, 1><<<1024, 256, 0, stream>>>(k_, nullptr, bufA, FRAG(3, 0), FRAG(3, 1), PRMI(3));
    conv_fused<1, 1><<<1024, 256, 0, stream>>>(bufA, nullptr, bufB, FRAG(4, 0), FRAG(4, 1), PRMI(4));
    lif_kern<<<512, 256, 0, stream>>>(bufB, vmask, 1.0f);

    kv_kern<<<256, 256, 0, stream>>>(kmask, vmask, kvb);
    attn_kern<<<512, 256, 0, stream>>>(qmask, kvb, amask);

    // final conv5: spike-input, standard-layout output
    conv_fused<2, 0><<<1024, 256, 0, stream>>>(nullptr, amask, (float*)d_out, FRAG(5, 0), FRAG(5, 1), PRMI(5));
}

// Round 6
// 1033.683 us; speedup vs baseline: 3.5627x; 1.0145x over previous
//
#include <hip/hip_runtime.h>

#define C 256
#define NPOS 2048
#define BB 8
#define TTIME 4
#define PRM_STRIDE 132096  // w1fT 65536 | w2fT 65536 | w3T 768 | bias 256
#define FRAG_ELEMS 196608  // 8 ks * 16 mt * 3 s * 64 lane * 8 j (bf16)

typedef float f32x4 __attribute__((ext_vector_type(4)));
typedef short short8 __attribute__((ext_vector_type(8)));
typedef unsigned int u32x4 __attribute__((ext_vector_type(4)));

static __device__ __forceinline__ unsigned short f2bf(float f) {
    unsigned int u = __float_as_uint(f);
    return (unsigned short)((u + 0x7FFFu + ((u >> 16) & 1u)) >> 16);
}
static __device__ __forceinline__ float bf2f(unsigned short b) {
    return __uint_as_float(((unsigned int)b) << 16);
}
static __device__ __forceinline__ void split3(float f, unsigned short& h,
                                              unsigned short& m, unsigned short& l) {
    h = f2bf(f);
    float r1 = f - bf2f(h);
    m = f2bf(r1);
    float r2 = r1 - bf2f(m);
    l = f2bf(r2);
}
static __device__ __forceinline__ unsigned long long pack4(const unsigned short* a) {
    return (unsigned long long)a[0] | ((unsigned long long)a[1] << 16)
         | ((unsigned long long)a[2] << 32) | ((unsigned long long)a[3] << 48);
}

// ---------------- PREP1: fold BN params into conv weights (f32) ----------------
__global__ __launch_bounds__(256) void prep_kern(
    const float* __restrict__ w1g, const float* __restrict__ bn1,
    const float* __restrict__ w3g, const float* __restrict__ w2g,
    const float* __restrict__ bn2, const float* __restrict__ bno,
    float* __restrict__ prm)
{
    int i = blockIdx.x;
    int tid = threadIdx.x;
    __shared__ float s1l[C], hcl[C], SGl[C];
    const float* b1 = bn1 + i * 4 * C;
    const float* b2 = bn2 + i * 4 * C;
    const float* bo = bno + i * 4 * C;
    float g1 = b1[tid], be1 = b1[C + tid], mu1 = b1[2 * C + tid], va1 = b1[3 * C + tid];
    float s1 = g1 / sqrtf(va1 + 1e-5f);
    float h1 = be1 - mu1 * s1;
    float g2 = b2[tid], be2 = b2[C + tid], mu2 = b2[2 * C + tid], va2 = b2[3 * C + tid];
    float s2 = g2 / sqrtf(va2 + 1e-5f);
    float h2 = be2 - mu2 * s2;
    float go = bo[tid], beo = bo[C + tid], muo = bo[2 * C + tid], vao = bo[3 * C + tid];
    float so = go / sqrtf(vao + 1e-5f);
    float ho = beo - muo * so;
    float SG = so * s2;
    float SH = so * h2 + ho;
    const float* w3i = w3g + i * C * 3;
    float w3s = w3i[tid * 3 + 0] + w3i[tid * 3 + 1] + w3i[tid * 3 + 2];
    s1l[tid] = s1; hcl[tid] = w3s * h1; SGl[tid] = SG;
    __syncthreads();
    float* prmi = prm + (size_t)i * PRM_STRIDE;
    const float* w1i = w1g + (size_t)i * C * C;
    const float* w2i = w2g + (size_t)i * C * C;
    for (int k = 0; k < C; ++k)
        prmi[tid * C + k] = s1l[k] * w1i[k * C + tid];
    for (int k = 0; k < C; ++k)
        prmi[65536 + tid * C + k] = SGl[k] * w2i[k * C + tid];
    for (int j = 0; j < 3; ++j)
        prmi[131072 + j * C + tid] = w3i[tid * 3 + j];
    float dot = 0.f;
    for (int k = 0; k < C; ++k)
        dot = fmaf(w2i[tid * C + k], hcl[k], dot);
    prmi[131840 + tid] = SG * dot + SH;
}

// ---------------- PREP2: build bf16x3 MFMA A-fragments ----------------
// frag layout: ((((ks*16 + mt)*3 + s)*64 + lane)*8 + j)
// lane l holds A[m = mt*16 + (l&15)][k = ks*32 + (l>>4)*8 + j]
__global__ __launch_bounds__(256) void prep2_kern(
    const float* __restrict__ prm, unsigned short* __restrict__ frags)
{
    int b = blockIdx.x;           // 12 = 6 convs x 2 matrices
    int i = b >> 1, which = b & 1;
    const float* src = prm + (size_t)i * PRM_STRIDE + which * 65536;  // wT[k*256+m]
    unsigned short* dst = frags + (size_t)b * FRAG_ELEMS;
    for (int e = threadIdx.x; e < 65536; e += 256) {
        int m = e & 255, k = e >> 8;
        float w = src[k * 256 + m];
        unsigned short h, mi, lo;
        split3(w, h, mi, lo);
        int ks = k >> 5, kin = k & 31;
        int mt = m >> 4;
        int lane = (m & 15) | (((kin >> 3) & 3) << 4);
        int j = kin & 7;
        size_t base = ((size_t)(ks * 16 + mt) * 3) * 64 * 8 + lane * 8 + j;
        dst[base] = h;
        dst[base + 512] = mi;
        dst[base + 1024] = lo;
    }
}

// ---------------- FUSED conv: y = W2f * dw3(W1f * x) + bias ----------------
// IN_MODE: 0 = STD f32 [c][pos], 1 = TRS f32 [pos][c], 2 = SPIKE bitmask
// OUT_T:   1 = transposed yT[pos][c] (LDS-staged coalesced), 0 = standard y[c][pos]
// LDS: x planes (80 cols x 128 k, 2 phases) @ 0/20480/40960 (61440 B total)
//      t planes (64 cols x 128 k, 2 phases) @ 0/16384/32768 (time-disjoint)
//      epilogue stage (32 pos x 256 c f32 = 32768 B)       (time-disjoint)
template<int IN_MODE, int OUT_T>
__global__ __launch_bounds__(256, 2) void conv_fused(
    const float* __restrict__ x, const unsigned int* __restrict__ xmask,
    float* __restrict__ y, const unsigned short* __restrict__ fragA,
    const unsigned short* __restrict__ fragB, const float* __restrict__ prmi)
{
    __shared__ __align__(16) char lds[61440];
    const int tid = threadIdx.x;
    const int lane = tid & 63, wv = tid >> 6;
    const int ctile = blockIdx.x & 31;
    const int slice = blockIdx.x >> 5;
    const int l0 = ctile * 64;
    const int lo4 = lane & 15, rg = lane >> 4;
    const int PA[6] = {0, 0, 1, 0, 2, 1};
    const int PB[6] = {0, 1, 0, 2, 0, 1};

    int mt[4];
#pragma unroll
    for (int rt = 0; rt < 4; ++rt) mt[rt] = wv * 2 + (rt & 1) + ((rt >> 1) << 3);

    f32x4 acc1[4][5];
#pragma unroll
    for (int a = 0; a < 4; ++a)
#pragma unroll
        for (int b = 0; b < 5; ++b) acc1[a][b] = (f32x4)0.f;

    const short8* Ab1 = (const short8*)fragA;

    // ================= STAGE 1: u = W1f * x  (acc1[rt][ct], 80 staged cols) ====
    for (int p = 0; p < 2; ++p) {
        // ---- stage x planes: 80 cols x 128 k ----
#pragma unroll
        for (int it = 0; it < 5; ++it) {
            int u = it * 256 + tid;          // 1280 units
            int col = u % 80;
            int oct = u / 80;                // 0..15
            int gpos = l0 - 8 + col;
            int kq = p * 128 + oct * 8;
            bool ok = (unsigned)gpos < (unsigned)NPOS;
            char* wb = lds + col * 256 + (((oct ^ (col & 7)) & 15) << 4);
            if (IN_MODE == 2) {
                u32x4 hp = (u32x4)0u;
                if (ok) {
                    const unsigned int* mg = xmask + (size_t)slice * C * 64 + (gpos >> 5);
                    int bitp = gpos & 31;
#pragma unroll
                    for (int j2 = 0; j2 < 4; ++j2) {
                        unsigned int b0 = (mg[(kq + 2 * j2) * 64] >> bitp) & 1u;
                        unsigned int b1 = (mg[(kq + 2 * j2 + 1) * 64] >> bitp) & 1u;
                        hp[j2] = (b0 ? 0x3F80u : 0u) | ((b1 ? 0x3F80u : 0u) << 16);
                    }
                }
                *(u32x4*)wb = hp;
            } else {
                float xv[8];
                if (ok) {
                    if (IN_MODE == 0) {
                        const float* xg = x + (size_t)slice * C * NPOS + gpos;
#pragma unroll
                        for (int j = 0; j < 8; ++j)
                            xv[j] = xg[(size_t)(kq + j) * NPOS];
                    } else {
                        const float4* rp = (const float4*)(x + ((size_t)slice * NPOS + gpos) * C + kq);
                        float4 a = rp[0], b = rp[1];
                        xv[0] = a.x; xv[1] = a.y; xv[2] = a.z; xv[3] = a.w;
                        xv[4] = b.x; xv[5] = b.y; xv[6] = b.z; xv[7] = b.w;
                    }
                } else {
#pragma unroll
                    for (int j = 0; j < 8; ++j) xv[j] = 0.f;
                }
                unsigned short h[8], m[8], l[8];
#pragma unroll
                for (int j = 0; j < 8; ++j) split3(xv[j], h[j], m[j], l[j]);
                u32x4 hp, mp, lp;
#pragma unroll
                for (int j2 = 0; j2 < 4; ++j2) {
                    hp[j2] = (unsigned int)h[2 * j2] | ((unsigned int)h[2 * j2 + 1] << 16);
                    mp[j2] = (unsigned int)m[2 * j2] | ((unsigned int)m[2 * j2 + 1] << 16);
                    lp[j2] = (unsigned int)l[2 * j2] | ((unsigned int)l[2 * j2 + 1] << 16);
                }
                *(u32x4*)wb = hp;
                *(u32x4*)(wb + 20480) = mp;
                *(u32x4*)(wb + 40960) = lp;
            }
        }
        __syncthreads();
        // ---- MFMA this K-phase: ks = p*4 .. p*4+3 ----
#pragma unroll
        for (int ksl = 0; ksl < 4; ++ksl) {
            int ks = p * 4 + ksl;
            int oct = ksl * 4 + rg;          // 0..15
            short8 A[4][3];
#pragma unroll
            for (int rt = 0; rt < 4; ++rt)
#pragma unroll
                for (int s = 0; s < 3; ++s)
                    A[rt][s] = Ab1[(size_t)((ks * 16 + mt[rt]) * 3 + s) * 64 + lane];
            int ba[5];
#pragma unroll
            for (int ct = 0; ct < 5; ++ct) {
                int colb = ct * 16 + lo4;
                ba[ct] = colb * 256 + (((oct ^ (colb & 7)) & 15) << 4);
            }
            if (IN_MODE == 2) {
                short8 B[5];
#pragma unroll
                for (int ct = 0; ct < 5; ++ct)
                    B[ct] = *(const short8*)(lds + ba[ct]);
                __builtin_amdgcn_s_setprio(1);
#pragma unroll
                for (int pp = 0; pp < 3; ++pp)
#pragma unroll
                    for (int rt = 0; rt < 4; ++rt)
#pragma unroll
                        for (int ct = 0; ct < 5; ++ct)
                            acc1[rt][ct] = __builtin_amdgcn_mfma_f32_16x16x32_bf16(
                                A[rt][pp], B[ct], acc1[rt][ct], 0, 0, 0);
                __builtin_amdgcn_s_setprio(0);
            } else {
                short8 B[5][3];
#pragma unroll
                for (int ct = 0; ct < 5; ++ct) {
                    B[ct][0] = *(const short8*)(lds + ba[ct]);
                    B[ct][1] = *(const short8*)(lds + 20480 + ba[ct]);
                    B[ct][2] = *(const short8*)(lds + 40960 + ba[ct]);
                }
                __builtin_amdgcn_s_setprio(1);
#pragma unroll
                for (int pp = 0; pp < 6; ++pp)
#pragma unroll
                    for (int rt = 0; rt < 4; ++rt)
#pragma unroll
                        for (int ct = 0; ct < 5; ++ct)
                            acc1[rt][ct] = __builtin_amdgcn_mfma_f32_16x16x32_bf16(
                                A[rt][PA[pp]], B[ct][PB[pp]], acc1[rt][ct], 0, 0, 0);
                __builtin_amdgcn_s_setprio(0);
            }
        }
        __syncthreads();
    }

    // ================= STAGE 2: y = W2f * dw3(u) =================
    const float* w3p = prmi + 131072;
    const short8* Ab2 = (const short8*)fragB;
    f32x4 acc2[4][4];
#pragma unroll
    for (int a = 0; a < 4; ++a)
#pragma unroll
        for (int b = 0; b < 4; ++b) acc2[a][b] = (f32x4)0.f;

    for (int tp = 0; tp < 2; ++tp) {
        // ---- depthwise (register shuffles) + split3 + t-plane write ----
#pragma unroll
        for (int rr = 0; rr < 2; ++rr) {
            int rt = tp * 2 + rr;
            int RTB = mt[rt] << 4;
            float w3a[4], w3b[4], w3c[4];
#pragma unroll
            for (int r = 0; r < 4; ++r) {
                int m = RTB + rg * 4 + r;
                w3a[r] = w3p[m]; w3b[r] = w3p[256 + m]; w3c[r] = w3p[512 + m];
            }
            int k0 = (RTB & 127) + rg * 4;
#pragma unroll
            for (int ct = 0; ct < 5; ++ct) {
                int sc = ct * 16 + lo4;
                unsigned short th[4], tm_[4], tl_[4];
#pragma unroll
                for (int r = 0; r < 4; ++r) {
                    float cur = acc1[rt][ct][r];
                    float prevv = acc1[rt][ct > 0 ? ct - 1 : 0][r];
                    float nextv = acc1[rt][ct < 4 ? ct + 1 : 4][r];
                    float sL  = __shfl(cur, lane - 1);
                    float sL2 = __shfl(prevv, lane + 15);
                    float sR  = __shfl(cur, lane + 1);
                    float sR2 = __shfl(nextv, lane - 15);
                    float uL = lo4 ? sL : sL2;
                    float uR = (lo4 == 15) ? sR2 : sR;
                    float t = w3a[r] * uL + w3b[r] * cur + w3c[r] * uR;
                    split3(t, th[r], tm_[r], tl_[r]);
                }
                if (sc >= 8 && sc < 72) {
                    int oc = sc - 8;
                    int base = oc * 256 + ((((k0 >> 3) ^ (oc & 7)) & 15) << 4) + (k0 & 7) * 2;
                    *(unsigned long long*)(lds + base) = pack4(th);
                    *(unsigned long long*)(lds + 16384 + base) = pack4(tm_);
                    *(unsigned long long*)(lds + 32768 + base) = pack4(tl_);
                }
            }
        }
        __syncthreads();
        // ---- MFMA: ks = tp*4 .. tp*4+3 ----
#pragma unroll
        for (int ksl = 0; ksl < 4; ++ksl) {
            int ks = tp * 4 + ksl;
            int chunk = ksl * 4 + rg;        // 0..15
            short8 A[4][3];
#pragma unroll
            for (int rt = 0; rt < 4; ++rt)
#pragma unroll
                for (int s = 0; s < 3; ++s)
                    A[rt][s] = Ab2[(size_t)((ks * 16 + mt[rt]) * 3 + s) * 64 + lane];
            short8 B[4][3];
#pragma unroll
            for (int ct = 0; ct < 4; ++ct) {
                int oc = ct * 16 + lo4;
                int ba = oc * 256 + (((chunk ^ (oc & 7)) & 15) << 4);
                B[ct][0] = *(const short8*)(lds + ba);
                B[ct][1] = *(const short8*)(lds + 16384 + ba);
                B[ct][2] = *(const short8*)(lds + 32768 + ba);
            }
            __builtin_amdgcn_s_setprio(1);
#pragma unroll
            for (int pp = 0; pp < 6; ++pp)
#pragma unroll
                for (int rt = 0; rt < 4; ++rt)
#pragma unroll
                    for (int ct = 0; ct < 4; ++ct)
                        acc2[rt][ct] = __builtin_amdgcn_mfma_f32_16x16x32_bf16(
                            A[rt][PA[pp]], B[ct][PB[pp]], acc2[rt][ct], 0, 0, 0);
            __builtin_amdgcn_s_setprio(0);
        }
        if (tp == 0) __syncthreads();
    }

    // ================= epilogue =================
    const float* bs = prmi + 131840;
    float* yS = y + (size_t)slice * NPOS * C;
    if (OUT_T) {
        // LDS-staged transpose: 2 phases of 32 pos x 256 ch (32 KB), then
        // fully-coalesced 1KB-per-wave row stores.
#pragma unroll
        for (int ph = 0; ph < 2; ++ph) {
            __syncthreads();
#pragma unroll
            for (int rt = 0; rt < 4; ++rt) {
                int m0 = (mt[rt] << 4) + rg * 4;
                int chunk = (mt[rt] << 2) + rg;       // m0/4, 0..63
#pragma unroll
                for (int cc = 0; cc < 2; ++cc) {
                    int ct = ph * 2 + cc;
                    int cl = cc * 16 + lo4;           // 0..31
                    f32x4 o;
#pragma unroll
                    for (int r = 0; r < 4; ++r) o[r] = acc2[rt][ct][r] + bs[m0 + r];
                    *(f32x4*)(lds + cl * 1024 + ((chunk ^ (cl & 7)) << 4)) = o;
                }
            }
            __syncthreads();
#pragma unroll
            for (int i = 0; i < 8; ++i) {
                int u = i * 256 + tid;                // 2048 units of 16B
                int cl = u >> 6, cchunk = u & 63;
                f32x4 o = *(const f32x4*)(lds + cl * 1024 + ((cchunk ^ (cl & 7)) << 4));
                int pos = l0 + ph * 32 + cl;
                *(f32x4*)(yS + (size_t)pos * C + cchunk * 4) = o;
            }
        }
    } else {
#pragma unroll
        for (int rt = 0; rt < 4; ++rt) {
            int m0 = (mt[rt] << 4) + rg * 4;
#pragma unroll
            for (int ct = 0; ct < 4; ++ct) {
                int pos = l0 + ct * 16 + lo4;
#pragma unroll
                for (int r = 0; r < 4; ++r)
                    yS[(size_t)(m0 + r) * NPOS + pos] = acc2[rt][ct][r] + bs[m0 + r];
            }
        }
    }
}

// ---------------- LIF + bitpack over T timesteps (reads yT[pos][c]) ----------------
__global__ __launch_bounds__(256) void lif_kern(
    const float* __restrict__ yT, unsigned int* __restrict__ mask, float vth)
{
    int g = blockIdx.x * 256 + threadIdx.x;   // 131072 = 8b x 64w x 256ch
    int ch = g & 255;
    int w = (g >> 8) & 63;
    int b = g >> 14;
    float v[32];
#pragma unroll
    for (int j = 0; j < 32; ++j) v[j] = 0.f;
    for (int t = 0; t < TTIME; ++t) {
        int slice = t * BB + b;
        const float* yr = yT + ((size_t)slice * NPOS + w * 32) * C + ch;
        unsigned int mw = 0;
#pragma unroll
        for (int j = 0; j < 32; ++j) {
            float yy = yr[(size_t)j * C];
            float vn = v[j] + (yy - v[j]) * 0.5f;
            int sp = (vn - vth) >= 0.0f;
            mw |= ((unsigned int)sp) << j;
            v[j] = sp ? 0.f : vn;
        }
        mask[((size_t)slice * C + ch) * 64 + w] = mw;
    }
}

// ---------------- kv popcount ----------------
__global__ __launch_bounds__(256) void kv_kern(
    const unsigned int* __restrict__ km_g, const unsigned int* __restrict__ vm_g,
    int* __restrict__ kv_g)
{
    int blk = blockIdx.x;
    int h = blk & 7;
    int tb = blk >> 3;
    __shared__ unsigned int km[32][65], vm[32][65];
    int tid = threadIdx.x;
#pragma unroll
    for (int i = 0; i < 8; ++i) {
        int idx = i * 256 + tid;
        int d = idx >> 6, w = idx & 63;
        size_t rb = ((size_t)tb * C + h * 32 + d) * 64 + w;
        km[d][w] = km_g[rb];
        vm[d][w] = vm_g[rb];
    }
    __syncthreads();
#pragma unroll
    for (int k = 0; k < 4; ++k) {
        int p = k * 256 + tid;
        int d = p >> 5, e = p & 31;
        int s = 0;
#pragma unroll
        for (int w = 0; w < 64; ++w)
            s += __popc(km[d][w] & vm[e][w]);
        kv_g[(size_t)blk * 1024 + p] = s;
    }
}

// ---------------- attention + attn-LIF -> bit mask ----------------
__global__ __launch_bounds__(256) void attn_kern(
    const unsigned int* __restrict__ qm_g, const int* __restrict__ kv_g,
    unsigned int* __restrict__ amask)
{
    int blk = blockIdx.x;
    int chunk = blk & 7;
    int bh = blk >> 3;
    int h = bh & 7, b = bh >> 3;
    int tid = threadIdx.x;
    __shared__ int kvs[1024];
    __shared__ unsigned int qw[32][8];
    float v[32];
#pragma unroll
    for (int e = 0; e < 32; ++e) v[e] = 0.f;
    for (int t = 0; t < TTIME; ++t) {
        int tb = t * BB + b;
        __syncthreads();
#pragma unroll
        for (int k = 0; k < 4; ++k)
            kvs[k * 256 + tid] = kv_g[((size_t)tb * 8 + h) * 1024 + k * 256 + tid];
        {
            int d = tid >> 3, wi = tid & 7;
            qw[d][wi] = qm_g[((size_t)tb * C + h * 32 + d) * 64 + chunk * 8 + wi];
        }
        __syncthreads();
        int a[32];
#pragma unroll
        for (int e = 0; e < 32; ++e) a[e] = 0;
        int wsel = tid >> 5, bitp = tid & 31;
        for (int d = 0; d < 32; ++d) {
            if ((qw[d][wsel] >> bitp) & 1u) {
                const int* kr = &kvs[d * 32];
#pragma unroll
                for (int e = 0; e < 32; ++e) a[e] += kr[e];
            }
        }
#pragma unroll
        for (int e = 0; e < 32; ++e) {
            float f = (float)a[e] * 0.125f;
            v[e] = v[e] + (f - v[e]) * 0.5f;
            int sp = (v[e] - 0.5f) >= 0.0f;
            unsigned long long bb = __ballot(sp);
            if ((tid & 63) == 0) {
                int ch = h * 32 + e;
                unsigned long long* dst = (unsigned long long*)amask
                    + ((size_t)tb * C + ch) * 32 + chunk * 4 + (tid >> 6);
                *dst = bb;
            }
            if (sp) v[e] = 0.f;
        }
    }
}

extern "C" void kernel_launch(void* const* d_in, const int* in_sizes, int n_in,
                              void* d_out, int out_size, void* d_ws, size_t ws_size,
                              hipStream_t stream) {
    const float* q   = (const float*)d_in[0];
    const float* k_  = (const float*)d_in[1];
    const float* w1g = (const float*)d_in[2];
    const float* bn1 = (const float*)d_in[3];
    const float* w3g = (const float*)d_in[4];
    const float* w2g = (const float*)d_in[5];
    const float* bn2 = (const float*)d_in[6];
    const float* bno = (const float*)d_in[7];

    float* prm = (float*)d_ws;                                        // 792576 f32
    unsigned short* frags = (unsigned short*)(prm + 6 * PRM_STRIDE);  // 12*196608 bf16
    float* bufA = (float*)(frags + 12 * FRAG_ELEMS);                  // 16777216 f32
    float* bufB = bufA + 16777216;                                    // 16777216 f32
    unsigned int* qmask = (unsigned int*)(bufB + 16777216);           // 524288 u32 each
    unsigned int* kmask = qmask + 524288;
    unsigned int* vmask = kmask + 524288;
    int* kvb = (int*)(vmask + 524288);                                // 262144 i32
    unsigned int* amask = (unsigned int*)(kvb + 262144);              // 524288 u32

    prep_kern<<<6, 256, 0, stream>>>(w1g, bn1, w3g, w2g, bn2, bno, prm);
    prep2_kern<<<12, 256, 0, stream>>>(prm, frags);

#define FRAG(i, which) (frags + (size_t)((i) * 2 + (which)) * FRAG_ELEMS)
#define PRMI(i) (prm + (size_t)(i) * PRM_STRIDE)

    // q branch: conv0 -> LIF -> qmask
    conv_fused<0, 1><<<1024, 256, 0, stream>>>(q, nullptr, bufA, FRAG(0, 0), FRAG(0, 1), PRMI(0));
    lif_kern<<<512, 256, 0, stream>>>(bufA, qmask, 1.0f);
    // k branch: conv1 -> conv2 -> LIF -> kmask
    conv_fused<0, 1><<<1024, 256, 0, stream>>>(k_, nullptr, bufA, FRAG(1, 0), FRAG(1, 1), PRMI(1));
    conv_fused<1, 1><<<1024, 256, 0, stream>>>(bufA, nullptr, bufB, FRAG(2, 0), FRAG(2, 1), PRMI(2));
    lif_kern<<<512, 256, 0, stream>>>(bufB, kmask, 1.0f);
    // v branch: conv3 -> conv4 -> LIF -> vmask
    conv_fused<0, 1><<<1024, 256, 0, stream>>>(k_, nullptr, bufA, FRAG(3, 0), FRAG(3, 1), PRMI(3));
    conv_fused<1, 1><<<1024, 256, 0, stream>>>(bufA, nullptr, bufB, FRAG(4, 0), FRAG(4, 1), PRMI(4));
    lif_kern<<<512, 256, 0, stream>>>(bufB, vmask, 1.0f);

    kv_kern<<<256, 256, 0, stream>>>(kmask, vmask, kvb);
    attn_kern<<<512, 256, 0, stream>>>(qmask, kvb, amask);

    // final conv5: spike-input, standard-layout output
    conv_fused<2, 0><<<1024, 256, 0, stream>>>(nullptr, amask, (float*)d_out, FRAG(5, 0), FRAG(5, 1), PRMI(5));
}